// Round 20
// baseline (843.587 us; speedup 1.0000x reference)
//
#include <hip/hip_runtime.h>

// LSH (Reformer) attention. b=2, t=4096, e=512, h=8, d=64, n_hashes=8, bucket=64.
// All-f32. PASSING discrete recipe (round 13): partitionable threefry (o0^o1,
// ctr=(0,m)); no-FMA Horner erfinv + Eigen-plog; x@w_qk no-FMA mul/add kc=320;
// bucket einsum mul/add K=64. Round 20: fused pv3 moved to 512 threads/block
// (same LDS -> 2 blocks/CU but 16 waves/CU, was 8): staging 4 thr/row,
// dots 2q x 8k, PV 2q x 4d. Same per-output op order -> bitwise identical.

#define DI static __device__ __forceinline__

constexpr int Tn = 4096, En = 512, Dn = 64, NH = 8, TT = 32768;

// ---------------- threefry2x32 (key = [0,42]) ----------------
DI unsigned rotl32(unsigned v, int d){ return (v << d) | (v >> (32 - d)); }

DI void threefry_0_42(unsigned c0, unsigned c1, unsigned &o0, unsigned &o1){
  const unsigned k0 = 0u, k1 = 42u;
  const unsigned k2 = 0x1BD11BDAu ^ k0 ^ k1;
  unsigned x0 = c0 + k0, x1 = c1 + k1;
#define RND(rr) { x0 += x1; x1 = rotl32(x1, rr); x1 ^= x0; }
  RND(13) RND(15) RND(26) RND(6)  x0 += k1; x1 += k2 + 1u;
  RND(17) RND(29) RND(16) RND(24) x0 += k2; x1 += k0 + 2u;
  RND(13) RND(15) RND(26) RND(6)  x0 += k0; x1 += k1 + 3u;
  RND(17) RND(29) RND(16) RND(24) x0 += k1; x1 += k2 + 4u;
  RND(13) RND(15) RND(26) RND(6)  x0 += k2; x1 += k0 + 5u;
#undef RND
  o0 = x0; o1 = x1;
}

// ---------------- XLA CPU log.f32 rewrite = Eigen plog_float, NO fma ------------
DI float xla_logf(float xin){
  float x = fmaxf(xin, __uint_as_float(0x00800000u));
  unsigned ib = __float_as_uint(x);
  float e = (float)((int)(ib >> 23) - 126);
  x = __uint_as_float((ib & 0x807fffffu) | 0x3f000000u);
  float mask = (x < __uint_as_float(0x3F3504F3u)) ? 1.0f : 0.0f;
  float tmp = __fmul_rn(mask, x);
  x = __fsub_rn(x, 1.0f);
  e = __fsub_rn(e, mask);
  x = __fadd_rn(x, tmp);
  float x2 = __fmul_rn(x, x);
  float x3 = __fmul_rn(x2, x);
  float y  = __fadd_rn(__fmul_rn( 7.0376836292e-2f, x), -1.1514610310e-1f);
  float y1 = __fadd_rn(__fmul_rn(-1.2420140846e-1f, x),  1.4249322787e-1f);
  float y2 = __fadd_rn(__fmul_rn( 2.0000714765e-1f, x), -2.4999993993e-1f);
  y  = __fadd_rn(__fmul_rn(y,  x),  1.1676998740e-1f);
  y1 = __fadd_rn(__fmul_rn(y1, x), -1.6668057665e-1f);
  y2 = __fadd_rn(__fmul_rn(y2, x),  3.3333331174e-1f);
  y  = __fadd_rn(__fmul_rn(y, x3), y1);
  y  = __fadd_rn(__fmul_rn(y, x3), y2);
  y  = __fmul_rn(y, x3);
  y1 = __fmul_rn(e, -2.12194440e-4f);
  y2 = __fmul_rn(x2, 0.5f);
  y  = __fadd_rn(y, y1);
  x  = __fsub_rn(x, y2);
  y2 = __fmul_rn(e, 0.693359375f);
  x  = __fadd_rn(x, y);
  x  = __fadd_rn(x, y2);
  return x;
}

DI float xla_log1pf(float a){
  float fs = __fmul_rn(__fadd_rn(__fmul_rn(-0.5f, a), 1.0f), a);
  float fl = xla_logf(__fadd_rn(a, 1.0f));
  return (fabsf(a) < 1e-4f) ? fs : fl;
}

DI float bits_to_normal(unsigned bits){
  unsigned ub = (bits >> 9) | 0x3f800000u;
  float f = __fsub_rn(__uint_as_float(ub), 1.0f);
  const float lo = __uint_as_float(0xBF7FFFFFu);
  float x = __fadd_rn(__fmul_rn(f, 2.0f), lo);
  x = fmaxf(lo, x);
  float xx = __fmul_rn(x, x);
  float w = -xla_log1pf(-xx);
  float p;
  if (w < 5.0f){
    w = __fsub_rn(w, 2.5f);
    p = 2.81022636e-08f;
    p = __fadd_rn( 3.43273939e-07f, __fmul_rn(p, w));
    p = __fadd_rn(-3.5233877e-06f,  __fmul_rn(p, w));
    p = __fadd_rn(-4.39150654e-06f, __fmul_rn(p, w));
    p = __fadd_rn( 0.00021858087f,  __fmul_rn(p, w));
    p = __fadd_rn(-0.00125372503f,  __fmul_rn(p, w));
    p = __fadd_rn(-0.00417768164f,  __fmul_rn(p, w));
    p = __fadd_rn( 0.246640727f,    __fmul_rn(p, w));
    p = __fadd_rn( 1.50140941f,     __fmul_rn(p, w));
  } else {
    w = __fsub_rn(__fsqrt_rn(w), 3.0f);
    p = -0.000200214257f;
    p = __fadd_rn( 0.000100950558f, __fmul_rn(p, w));
    p = __fadd_rn( 0.00134934322f,  __fmul_rn(p, w));
    p = __fadd_rn(-0.00367342844f,  __fmul_rn(p, w));
    p = __fadd_rn( 0.00573950773f,  __fmul_rn(p, w));
    p = __fadd_rn(-0.0076224613f,   __fmul_rn(p, w));
    p = __fadd_rn( 0.00943887047f,  __fmul_rn(p, w));
    p = __fadd_rn( 1.00167406f,     __fmul_rn(p, w));
    p = __fadd_rn( 2.83297682f,     __fmul_rn(p, w));
  }
  float e = __fmul_rn(p, x);
  return __fmul_rn(__uint_as_float(0x3FB504F3u), e);
}

__global__ __launch_bounds__(256) void lsh_gen_rot(float* __restrict__ rot){
  int m = blockIdx.x * 256 + threadIdx.x;               // 0..16383
  unsigned o0, o1;
  threefry_0_42(0u, (unsigned)m, o0, o1);
  rot[m] = bits_to_normal(o0 ^ o1);
}

// ---------------- GEMM [8192x512]@[512x512], 64x64 tile, A+W in LDS -------------
template<int MODE, int KC, bool FMA>
__global__ __launch_bounds__(256) void lsh_gemm_t(const float* __restrict__ A,
                                                  const float* __restrict__ W,
                                                  const float* __restrict__ bias,
                                                  float* __restrict__ out){
  __shared__ float as[32][68];
  __shared__ float wsm[32][68];
  int rb = blockIdx.x, cb = blockIdx.y;
  int tid = threadIdx.x;
  int tr = (tid >> 4) << 2, tc = (tid & 15) << 2;
  float acc[4][4], tot[4][4];
#pragma unroll
  for (int i = 0; i < 4; ++i)
#pragma unroll
    for (int j = 0; j < 4; ++j){ acc[i][j] = 0.f; tot[i][j] = 0.f; }
  for (int k0 = 0; k0 < 512; k0 += 32){
    __syncthreads();
    for (int idx = tid; idx < 2048; idx += 256){
      int kk = idx & 31, r = idx >> 5;
      int row = rb * 64 + r, k = k0 + kk;
      float val;
      if (MODE == 0){
        val = A[(size_t)row * 512 + k];
      } else {
        int b = row >> 12, t = row & 4095, h = k >> 6, dd = k & 63;
        val = A[(((size_t)(b * 8 + h) * 4096) + t) * 64 + dd];
      }
      as[kk][r] = val;
    }
    for (int idx = tid; idx < 2048; idx += 256){
      int c = idx & 63, kk = idx >> 6;
      wsm[kk][c] = W[(size_t)(k0 + kk) * 512 + cb * 64 + c];
    }
    __syncthreads();
#pragma unroll
    for (int kk = 0; kk < 32; ++kk){
      int k = k0 + kk;
      if (!FMA && k && (k % KC) == 0){
#pragma unroll
        for (int i = 0; i < 4; ++i)
#pragma unroll
          for (int j = 0; j < 4; ++j){ tot[i][j] = __fadd_rn(tot[i][j], acc[i][j]); acc[i][j] = 0.f; }
      }
      float4 av = *(const float4*)&as[kk][tr];
      float4 wv = *(const float4*)&wsm[kk][tc];
      float ae[4] = {av.x, av.y, av.z, av.w};
      float we[4] = {wv.x, wv.y, wv.z, wv.w};
#pragma unroll
      for (int i = 0; i < 4; ++i)
#pragma unroll
        for (int j = 0; j < 4; ++j){
          if (FMA) acc[i][j] = fmaf(ae[i], we[j], acc[i][j]);
          else     acc[i][j] = __fadd_rn(acc[i][j], __fmul_rn(ae[i], we[j]));
        }
    }
  }
#pragma unroll
  for (int i = 0; i < 4; ++i){
#pragma unroll
    for (int j = 0; j < 4; ++j){
      float o = FMA ? acc[i][j] : __fadd_rn(tot[i][j], acc[i][j]);
      int col = cb * 64 + tc + j;
      if (MODE == 1) o += bias[col];
      out[(size_t)(rb * 64 + tr + i) * 512 + col] = o;
    }
  }
}

// ---------------- buckets: one round per block (grid z = 8) ----------------
__global__ __launch_bounds__(256) void lsh_buckets3(const float* __restrict__ qk,
                                                    const float* __restrict__ rot,
                                                    unsigned short* __restrict__ buckets){
  int bh = blockIdx.x, tile = blockIdx.y, r = blockIdx.z;
  int b = bh >> 3, h = bh & 7;
  int t = tile * 256 + threadIdx.x;
  __shared__ float rl[2048];
  float q[64];
  const float* qrow = qk + ((size_t)(b * Tn + t) * En + h * Dn);
#pragma unroll
  for (int f4 = 0; f4 < 16; ++f4){
    float4 v = *(const float4*)&qrow[f4 * 4];
    q[f4*4+0] = v.x; q[f4*4+1] = v.y; q[f4*4+2] = v.z; q[f4*4+3] = v.w;
  }
  for (int idx = threadIdx.x; idx < 2048; idx += 256)
    rl[idx] = rot[(idx >> 5) * 256 + r * 32 + (idx & 31)];
  __syncthreads();
  float acc[32];
#pragma unroll
  for (int i = 0; i < 32; ++i) acc[i] = 0.f;
#pragma unroll
  for (int f = 0; f < 64; ++f){
    float qf = q[f];
#pragma unroll
    for (int i = 0; i < 32; ++i) acc[i] = __fadd_rn(acc[i], __fmul_rn(qf, rl[f * 32 + i]));
  }
  float best = acc[0]; int bi = 0;
#pragma unroll
  for (int i = 1; i < 32; ++i) if (acc[i] > best){ best = acc[i]; bi = i; }
#pragma unroll
  for (int i = 0; i < 32; ++i){ float nv = -acc[i]; if (nv > best){ best = nv; bi = 32 + i; } }
  buckets[(size_t)bh * TT + r * Tn + t] = (unsigned short)(r * 64 + bi);
}

// ---------------- counting sort ----------------
__global__ __launch_bounds__(256) void lsh_hist(const unsigned short* __restrict__ buckets,
                                                unsigned int* __restrict__ counts){
  int idx = blockIdx.x * 256 + threadIdx.x;
  int bh = idx >> 15;
  atomicAdd(&counts[bh * 512 + buckets[idx]], 1u);
}

__global__ __launch_bounds__(512) void lsh_scan(const unsigned int* __restrict__ counts,
                                                unsigned int* __restrict__ starts){
  __shared__ unsigned int s[512];
  int bh = blockIdx.x, tid = threadIdx.x;
  unsigned int v = counts[bh * 512 + tid];
  s[tid] = v; __syncthreads();
  for (int off = 1; off < 512; off <<= 1){
    unsigned int add = (tid >= off) ? s[tid - off] : 0u;
    __syncthreads();
    s[tid] += add;
    __syncthreads();
  }
  starts[bh * 512 + tid] = s[tid] - v;
}

__global__ __launch_bounds__(256) void lsh_rank(const unsigned short* __restrict__ buckets,
                                                const unsigned int* __restrict__ starts,
                                                unsigned short* __restrict__ s2pos,
                                                unsigned short* __restrict__ pos2s){
  int bh = blockIdx.x >> 3, r = blockIdx.x & 7;
  __shared__ unsigned char lb[4096];
  __shared__ unsigned short cnt[64][4];
  const unsigned short* bsrc = buckets + (size_t)bh * TT + r * Tn;
  for (int t = threadIdx.x; t < 4096; t += 256) lb[t] = (unsigned char)(bsrc[t] - r * 64);
  __syncthreads();
  int b = threadIdx.x & 63, q = threadIdx.x >> 6;
  int c = 0;
  for (int t = q * 1024; t < (q + 1) * 1024; ++t) c += (lb[t] == b);
  cnt[b][q] = (unsigned short)c;
  __syncthreads();
  int off = 0;
  for (int q2 = 0; q2 < q; ++q2) off += cnt[b][q2];
  unsigned int run = starts[bh * 512 + r * 64 + b] + off;
  unsigned short* s2p = s2pos + (size_t)bh * TT;
  unsigned short* p2s = pos2s + (size_t)bh * TT + r * Tn;
  for (int t = q * 1024; t < (q + 1) * 1024; ++t){
    if (lb[t] == b){ s2p[run] = (unsigned short)t; p2s[t] = (unsigned short)run; run++; }
  }
}

#define KSTR 68
#define SWZ(row) ((((row) >> 3) & 7) << 2)

// ---------------- staging (256-thread variant, fallback path) ----------------
DI void stage_rows(const float* __restrict__ qk, const unsigned short* __restrict__ s2pos,
                   int bh, int b, int h, int c, int cprev,
                   float* kbuf, float* den, unsigned short* kt){
  int j = threadIdx.x >> 1, half = threadIdx.x & 1;
  int slot = (j < 64) ? (c * 64 + j) : (cprev * 64 + (j - 64));
  int t = s2pos[(size_t)bh * TT + slot];
  const float* row = qk + ((size_t)(b * Tn + t) * En + h * Dn);
  int sw = SWZ(j);
  float tmp[32]; float ss = 0.f;
#pragma unroll
  for (int dd = 0; dd < 32; ++dd){ float xv = row[half * 32 + dd]; tmp[dd] = xv; ss = fmaf(xv, xv, ss); }
  ss += __shfl_xor(ss, 1);
  float dn = sqrtf(ss) + 1e-6f;
#pragma unroll
  for (int d4 = 0; d4 < 8; ++d4){
    float4 o; o.x = tmp[4*d4] / dn; o.y = tmp[4*d4+1] / dn; o.z = tmp[4*d4+2] / dn; o.w = tmp[4*d4+3] / dn;
    *(float4*)&kbuf[j * KSTR + ((half * 32 + 4 * d4) ^ sw)] = o;
  }
  if (!half){ den[j] = dn; kt[j] = (unsigned short)t; }
}

// ---------------- register-tiled dots 4q x 8k (fallback path) ----------------
DI void dots_tile(const float* kbuf, const float* den, const unsigned short* kt,
                  int a, int bb, float dots[4][8]){
  int swq = SWZ(4 * a);
  int swk = SWZ(8 * bb);
#pragma unroll
  for (int qq = 0; qq < 4; ++qq)
#pragma unroll
    for (int kk = 0; kk < 8; ++kk) dots[qq][kk] = 0.f;
#pragma unroll
  for (int d4 = 0; d4 < 16; ++d4){
    float4 qv[4], kv[8];
#pragma unroll
    for (int qq = 0; qq < 4; ++qq) qv[qq] = *(const float4*)&kbuf[(4*a+qq) * KSTR + ((d4 * 4) ^ swq)];
#pragma unroll
    for (int kk = 0; kk < 8; ++kk) kv[kk] = *(const float4*)&kbuf[(8*bb+kk) * KSTR + ((d4 * 4) ^ swk)];
#pragma unroll
    for (int qq = 0; qq < 4; ++qq)
#pragma unroll
      for (int kk = 0; kk < 8; ++kk){
        dots[qq][kk] = fmaf(qv[qq].x, kv[kk].x, dots[qq][kk]);
        dots[qq][kk] = fmaf(qv[qq].y, kv[kk].y, dots[qq][kk]);
        dots[qq][kk] = fmaf(qv[qq].z, kv[kk].z, dots[qq][kk]);
        dots[qq][kk] = fmaf(qv[qq].w, kv[kk].w, dots[qq][kk]);
      }
  }
#pragma unroll
  for (int qq = 0; qq < 4; ++qq){
    float sc = den[4*a+qq] * 0.125f;
    int qt = kt[4*a+qq];
#pragma unroll
    for (int kk = 0; kk < 8; ++kk){
      float v = dots[qq][kk] * sc;
      if ((int)kt[8*bb+kk] == qt) v = -1e5f;
      dots[qq][kk] = v;
    }
  }
}

// ---------------- pass 1: per-slot LSE (fallback path) ----------------
__global__ __launch_bounds__(256) void lsh_lse2(const float* __restrict__ qk,
                                                const unsigned short* __restrict__ s2pos,
                                                float* __restrict__ lse){
  int bh = blockIdx.x >> 9, c = blockIdx.x & 511;
  int b = bh >> 3, h = bh & 7;
  int cprev = (c + 511) & 511;
  __shared__ float kbuf[128 * KSTR];
  __shared__ float den[128];
  __shared__ unsigned short kt[128];
  __shared__ float red2[64][17];
  __shared__ float Marr[64];
  stage_rows(qk, s2pos, bh, b, h, c, cprev, kbuf, den, kt);
  __syncthreads();
  int a = threadIdx.x & 15, bb = threadIdx.x >> 4;
  float dots[4][8];
  dots_tile(kbuf, den, kt, a, bb, dots);
#pragma unroll
  for (int qq = 0; qq < 4; ++qq){
    float m = dots[qq][0];
#pragma unroll
    for (int kk = 1; kk < 8; ++kk) m = fmaxf(m, dots[qq][kk]);
    red2[4*a+qq][bb] = m;
  }
  __syncthreads();
  if (threadIdx.x < 64){
    float M = red2[threadIdx.x][0];
#pragma unroll
    for (int j = 1; j < 16; ++j) M = fmaxf(M, red2[threadIdx.x][j]);
    Marr[threadIdx.x] = M;
  }
  __syncthreads();
  float ssum[4];
#pragma unroll
  for (int qq = 0; qq < 4; ++qq){
    float M = Marr[4*a+qq];
    float s = 0.f;
#pragma unroll
    for (int kk = 0; kk < 8; ++kk) s += expf(dots[qq][kk] - M);
    ssum[qq] = s;
  }
  __syncthreads();
#pragma unroll
  for (int qq = 0; qq < 4; ++qq) red2[4*a+qq][bb] = ssum[qq];
  __syncthreads();
  if (threadIdx.x < 64){
    float S = 0.f;
#pragma unroll
    for (int j = 0; j < 16; ++j) S += red2[threadIdx.x][j];
    lse[(size_t)bh * TT + c * 64 + threadIdx.x] = Marr[threadIdx.x] + logf(S);
  }
}

// ---------------- per-(bh,t) round weights (fallback path) ----------------
__global__ __launch_bounds__(256) void lsh_wgt(const float* __restrict__ lse,
                                               const unsigned short* __restrict__ pos2s,
                                               float* __restrict__ wgt){
  int idx = blockIdx.x * 256 + threadIdx.x;
  int bh = idx >> 12, t = idx & 4095;
  float l[8];
#pragma unroll
  for (int r = 0; r < 8; ++r){
    int s = pos2s[(size_t)bh * TT + r * Tn + t];
    l[r] = lse[(size_t)bh * TT + s];
  }
  float M = l[0];
#pragma unroll
  for (int r = 1; r < 8; ++r) M = fmaxf(M, l[r]);
  float S = 0.f;
#pragma unroll
  for (int r = 0; r < 8; ++r) S += expf(l[r] - M);
  float L = M + logf(S);
#pragma unroll
  for (int r = 0; r < 8; ++r) wgt[(size_t)(bh * 8 + r) * Tn + t] = expf(l[r] - L);
}

// ---------------- fused pv (512 threads): dots + LSE + PV -> so, lse ------------
__global__ __launch_bounds__(512) void lsh_pv4(const float* __restrict__ qk,
                                               const float* __restrict__ vv,
                                               const unsigned short* __restrict__ s2pos,
                                               float* __restrict__ lse,
                                               float* __restrict__ so){
  int r = blockIdx.y;
  int bh = blockIdx.x >> 6, cc = blockIdx.x & 63;
  int c = r * 64 + cc, cprev = (c + 511) & 511;
  int b = bh >> 3, h = bh & 7;
  __shared__ float kbuf[128 * KSTR];          // aliased later as P[64][132]
  __shared__ float vbuf[128 * KSTR];          // head aliased as reduce scratch
  __shared__ float den[128];
  __shared__ unsigned short kt[128];
  float (*red2)[17] = (float(*)[17])vbuf;     // [64][17]
  float* Marr = vbuf + 64 * 17;               // [64]
  int tid = threadIdx.x;
  // ---- stage: 4 threads per row ----
  {
    int j = tid >> 2, quarter = tid & 3;
    int slot = (j < 64) ? (c * 64 + j) : (cprev * 64 + (j - 64));
    int t = s2pos[(size_t)bh * TT + slot];
    const float* row = qk + ((size_t)(b * Tn + t) * En + h * Dn);
    int sw = SWZ(j);
    float tmp[16]; float ss = 0.f;
#pragma unroll
    for (int dd = 0; dd < 16; ++dd){ float xv = row[quarter * 16 + dd]; tmp[dd] = xv; ss = fmaf(xv, xv, ss); }
    ss += __shfl_xor(ss, 1);
    ss += __shfl_xor(ss, 2);
    float dn = sqrtf(ss) + 1e-6f;
#pragma unroll
    for (int d4 = 0; d4 < 4; ++d4){
      float4 o; o.x = tmp[4*d4] / dn; o.y = tmp[4*d4+1] / dn; o.z = tmp[4*d4+2] / dn; o.w = tmp[4*d4+3] / dn;
      *(float4*)&kbuf[j * KSTR + ((quarter * 16 + 4 * d4) ^ sw)] = o;
    }
    if (!quarter){ den[j] = dn; kt[j] = (unsigned short)t; }
  }
  __syncthreads();
  // ---- dots: thread = 2q x 8k ----
  int a = tid & 31, bb = tid >> 5;            // a: 32 groups of 2q; bb: 16 groups of 8k
  float dots[2][8];
  {
    int swq = SWZ(2 * a), swk = SWZ(8 * bb);
#pragma unroll
    for (int qq = 0; qq < 2; ++qq)
#pragma unroll
      for (int kk = 0; kk < 8; ++kk) dots[qq][kk] = 0.f;
#pragma unroll
    for (int d4 = 0; d4 < 16; ++d4){
      float4 qv[2], kv[8];
#pragma unroll
      for (int qq = 0; qq < 2; ++qq) qv[qq] = *(const float4*)&kbuf[(2*a+qq) * KSTR + ((d4 * 4) ^ swq)];
#pragma unroll
      for (int kk = 0; kk < 8; ++kk) kv[kk] = *(const float4*)&kbuf[(8*bb+kk) * KSTR + ((d4 * 4) ^ swk)];
#pragma unroll
      for (int qq = 0; qq < 2; ++qq)
#pragma unroll
        for (int kk = 0; kk < 8; ++kk){
          dots[qq][kk] = fmaf(qv[qq].x, kv[kk].x, dots[qq][kk]);
          dots[qq][kk] = fmaf(qv[qq].y, kv[kk].y, dots[qq][kk]);
          dots[qq][kk] = fmaf(qv[qq].z, kv[kk].z, dots[qq][kk]);
          dots[qq][kk] = fmaf(qv[qq].w, kv[kk].w, dots[qq][kk]);
        }
    }
#pragma unroll
    for (int qq = 0; qq < 2; ++qq){
      float sc = den[2*a+qq] * 0.125f;
      int qt = kt[2*a+qq];
#pragma unroll
      for (int kk = 0; kk < 8; ++kk){
        float v = dots[qq][kk] * sc;
        if ((int)kt[8*bb+kk] == qt) v = -1e5f;
        dots[qq][kk] = v;
      }
    }
  }
  // ---- in-block LSE ----
#pragma unroll
  for (int qq = 0; qq < 2; ++qq){
    float m = dots[qq][0];
#pragma unroll
    for (int kk = 1; kk < 8; ++kk) m = fmaxf(m, dots[qq][kk]);
    red2[2*a+qq][bb] = m;
  }
  __syncthreads();
  if (tid < 64){
    float M = red2[tid][0];
#pragma unroll
    for (int j = 1; j < 16; ++j) M = fmaxf(M, red2[tid][j]);
    Marr[tid] = M;
  }
  __syncthreads();
  float ssum[2];
#pragma unroll
  for (int qq = 0; qq < 2; ++qq){
    float M = Marr[2*a+qq];
    float s = 0.f;
#pragma unroll
    for (int kk = 0; kk < 8; ++kk) s += expf(dots[qq][kk] - M);
    ssum[qq] = s;
  }
  __syncthreads();
#pragma unroll
  for (int qq = 0; qq < 2; ++qq) red2[2*a+qq][bb] = ssum[qq];
  __syncthreads();
  if (tid < 64){
    float S = 0.f;
#pragma unroll
    for (int j = 0; j < 16; ++j) S += red2[tid][j];
    float lv = Marr[tid] + logf(S);
    lse[(size_t)bh * TT + c * 64 + tid] = lv;
    Marr[tid] = lv;
  }
  __syncthreads();
  float lrow[2];
#pragma unroll
  for (int qq = 0; qq < 2; ++qq) lrow[qq] = Marr[2*a+qq];
#pragma unroll
  for (int qq = 0; qq < 2; ++qq)
#pragma unroll
    for (int kk = 0; kk < 8; ++kk) dots[qq][kk] = expf(dots[qq][kk] - lrow[qq]);
  __syncthreads();                            // reduce-scratch + K reads done
  // ---- write P (swizzled) into kbuf alias; stage V (swizzled) into vbuf ----
  float* pb = kbuf;
  {
    int swp = SWZ(2 * a);
#pragma unroll
    for (int qq = 0; qq < 2; ++qq){
      *(float4*)&pb[(2*a+qq) * 132 + ((8*bb)     ^ swp)] = make_float4(dots[qq][0], dots[qq][1], dots[qq][2], dots[qq][3]);
      *(float4*)&pb[(2*a+qq) * 132 + ((8*bb + 4) ^ swp)] = make_float4(dots[qq][4], dots[qq][5], dots[qq][6], dots[qq][7]);
    }
  }
  {
    int j = tid >> 2, quarter = tid & 3;
    int t = kt[j];
    int sw = SWZ(j);
    const float* row = vv + ((size_t)(b * Tn + t) * En + h * Dn);
#pragma unroll
    for (int d4 = 0; d4 < 4; ++d4){
      float4 o;
      o.x = row[quarter*16 + 4*d4]; o.y = row[quarter*16 + 4*d4 + 1];
      o.z = row[quarter*16 + 4*d4 + 2]; o.w = row[quarter*16 + 4*d4 + 3];
      *(float4*)&vbuf[j * KSTR + ((quarter * 16 + 4 * d4) ^ sw)] = o;
    }
  }
  __syncthreads();
  // ---- PV: thread = 2q x 4d ----
  int qg = tid & 31, dg = tid >> 5;
  float acc[2][4];
#pragma unroll
  for (int qq = 0; qq < 2; ++qq)
#pragma unroll
    for (int dd = 0; dd < 4; ++dd) acc[qq][dd] = 0.f;
  int swp = SWZ(2 * qg);
  for (int k4 = 0; k4 < 32; ++k4){
    int swv = SWZ(4 * k4);
    float4 pr[2], vr[4];
#pragma unroll
    for (int qq = 0; qq < 2; ++qq) pr[qq] = *(const float4*)&pb[(2*qg+qq) * 132 + ((k4 * 4) ^ swp)];
#pragma unroll
    for (int kk = 0; kk < 4; ++kk) vr[kk] = *(const float4*)&vbuf[(k4*4+kk) * KSTR + ((4*dg) ^ swv)];
#pragma unroll
    for (int kk = 0; kk < 4; ++kk){
#pragma unroll
      for (int qq = 0; qq < 2; ++qq){
        float p = (kk == 0) ? pr[qq].x : (kk == 1) ? pr[qq].y : (kk == 2) ? pr[qq].z : pr[qq].w;
        acc[qq][0] = fmaf(p, vr[kk].x, acc[qq][0]);
        acc[qq][1] = fmaf(p, vr[kk].y, acc[qq][1]);
        acc[qq][2] = fmaf(p, vr[kk].z, acc[qq][2]);
        acc[qq][3] = fmaf(p, vr[kk].w, acc[qq][3]);
      }
    }
  }
#pragma unroll
  for (int qq = 0; qq < 2; ++qq){
    int i = 2*qg + qq;
    int qt = kt[i];
    float* srow = so + (((size_t)(bh * 8 + r) * Tn) + qt) * Dn + 4*dg;
    *(float4*)srow = make_float4(acc[qq][0], acc[qq][1], acc[qq][2], acc[qq][3]);
  }
}

// ---------------- combine: attn[bh][t] = sum_r exp(lse_r - LSE) * so[r] --------
__global__ __launch_bounds__(256) void lsh_comb(const float* __restrict__ lse,
                                                const unsigned short* __restrict__ pos2s,
                                                const float* __restrict__ so,
                                                float* __restrict__ attn){
  int idx = blockIdx.x * 256 + threadIdx.x;   // 16*4096
  int bh = idx >> 12, t = idx & 4095;
  float l[8];
#pragma unroll
  for (int r = 0; r < 8; ++r){
    int s = pos2s[(size_t)bh * TT + r * Tn + t];
    l[r] = lse[(size_t)bh * TT + s];
  }
  float M = l[0];
#pragma unroll
  for (int r = 1; r < 8; ++r) M = fmaxf(M, l[r]);
  float S = 0.f;
#pragma unroll
  for (int r = 0; r < 8; ++r) S += expf(l[r] - M);
  float L = M + logf(S);
  float acc[64];
#pragma unroll
  for (int d = 0; d < 64; ++d) acc[d] = 0.f;
  for (int r = 0; r < 8; ++r){
    float w = expf(l[r] - L);
    const float* srow = so + (((size_t)(bh * 8 + r) * Tn) + t) * Dn;
#pragma unroll
    for (int d4 = 0; d4 < 16; ++d4){
      float4 v = *(const float4*)&srow[d4 * 4];
      acc[4*d4+0] = fmaf(w, v.x, acc[4*d4+0]);
      acc[4*d4+1] = fmaf(w, v.y, acc[4*d4+1]);
      acc[4*d4+2] = fmaf(w, v.z, acc[4*d4+2]);
      acc[4*d4+3] = fmaf(w, v.w, acc[4*d4+3]);
    }
  }
  float* arow = attn + ((size_t)(bh * Tn + t)) * Dn;
#pragma unroll
  for (int d4 = 0; d4 < 16; ++d4)
    *(float4*)&arow[d4 * 4] = make_float4(acc[4*d4], acc[4*d4+1], acc[4*d4+2], acc[4*d4+3]);
}

// ---------------- pass 2 (fallback): probs, PV, direct += ----------------
__global__ __launch_bounds__(256) void lsh_pv2(const float* __restrict__ qk,
                                               const float* __restrict__ vv,
                                               const unsigned short* __restrict__ s2pos,
                                               const float* __restrict__ lse,
                                               const float* __restrict__ wgt,
                                               float* __restrict__ attn, int r){
  int bh = blockIdx.x >> 6, cc = blockIdx.x & 63;
  int c = r * 64 + cc, cprev = (c + 511) & 511;
  int b = bh >> 3, h = bh & 7;
  __shared__ float kbuf[128 * KSTR];
  __shared__ float vbuf[128 * KSTR];
  __shared__ float den[128];
  __shared__ unsigned short kt[128];
  stage_rows(qk, s2pos, bh, b, h, c, cprev, kbuf, den, kt);
  __syncthreads();
  int a = threadIdx.x & 15, bb = threadIdx.x >> 4;
  float dots[4][8];
  dots_tile(kbuf, den, kt, a, bb, dots);
  float lrow[4];
#pragma unroll
  for (int qq = 0; qq < 4; ++qq) lrow[qq] = lse[(size_t)bh * TT + c * 64 + 4*a+qq];
#pragma unroll
  for (int qq = 0; qq < 4; ++qq)
#pragma unroll
    for (int kk = 0; kk < 8; ++kk) dots[qq][kk] = expf(dots[qq][kk] - lrow[qq]);
  __syncthreads();
  float* pb = kbuf;
  {
    int swp = SWZ(4 * a);
#pragma unroll
    for (int qq = 0; qq < 4; ++qq){
      *(float4*)&pb[(4*a+qq) * 132 + ((8*bb)     ^ swp)] = make_float4(dots[qq][0], dots[qq][1], dots[qq][2], dots[qq][3]);
      *(float4*)&pb[(4*a+qq) * 132 + ((8*bb + 4) ^ swp)] = make_float4(dots[qq][4], dots[qq][5], dots[qq][6], dots[qq][7]);
    }
  }
  {
    int j = threadIdx.x >> 1, half = threadIdx.x & 1;
    int t = kt[j];
    int sw = SWZ(j);
    const float* row = vv + ((size_t)(b * Tn + t) * En + h * Dn);
#pragma unroll
    for (int d4 = 0; d4 < 8; ++d4){
      float4 o;
      o.x = row[half*32 + 4*d4]; o.y = row[half*32 + 4*d4 + 1];
      o.z = row[half*32 + 4*d4 + 2]; o.w = row[half*32 + 4*d4 + 3];
      *(float4*)&vbuf[j * KSTR + ((half * 32 + 4 * d4) ^ sw)] = o;
    }
  }
  __syncthreads();
  int qg = threadIdx.x & 15, dg = threadIdx.x >> 4;
  float acc[4][4];
#pragma unroll
  for (int qq = 0; qq < 4; ++qq)
#pragma unroll
    for (int dd = 0; dd < 4; ++dd) acc[qq][dd] = 0.f;
  int swp = SWZ(4 * qg);
  for (int k4 = 0; k4 < 32; ++k4){
    int swv = SWZ(4 * k4);
    float4 pr[4], vr[4];
#pragma unroll
    for (int qq = 0; qq < 4; ++qq) pr[qq] = *(const float4*)&pb[(4*qg+qq) * 132 + ((k4 * 4) ^ swp)];
#pragma unroll
    for (int kk = 0; kk < 4; ++kk) vr[kk] = *(const float4*)&vbuf[(k4*4+kk) * KSTR + ((4*dg) ^ swv)];
#pragma unroll
    for (int kk = 0; kk < 4; ++kk){
#pragma unroll
      for (int qq = 0; qq < 4; ++qq){
        float p = (kk == 0) ? pr[qq].x : (kk == 1) ? pr[qq].y : (kk == 2) ? pr[qq].z : pr[qq].w;
        acc[qq][0] = fmaf(p, vr[kk].x, acc[qq][0]);
        acc[qq][1] = fmaf(p, vr[kk].y, acc[qq][1]);
        acc[qq][2] = fmaf(p, vr[kk].z, acc[qq][2]);
        acc[qq][3] = fmaf(p, vr[kk].w, acc[qq][3]);
      }
    }
  }
#pragma unroll
  for (int qq = 0; qq < 4; ++qq){
    int i = 4*qg + qq;
    int qt = kt[i];
    float w = wgt[(size_t)(bh * 8 + r) * Tn + qt];
    float* arow = attn + ((size_t)(bh * Tn + qt)) * Dn + 4*dg;
    float4 old = *(float4*)arow;
    old.x += w * acc[qq][0]; old.y += w * acc[qq][1];
    old.z += w * acc[qq][2]; old.w += w * acc[qq][3];
    *(float4*)arow = old;
  }
}

// ---------------- host ----------------
extern "C" void kernel_launch(void* const* d_in, const int* in_sizes, int n_in,
                              void* d_out, int out_size, void* d_ws, size_t ws_size,
                              hipStream_t stream){
  (void)in_sizes; (void)n_in; (void)out_size;
  const float* x    = (const float*)d_in[0];
  const float* wqk  = (const float*)d_in[1];
  const float* wv   = (const float*)d_in[2];
  const float* wout = (const float*)d_in[3];
  const float* bout = (const float*)d_in[4];
  float* out = (float*)d_out;
  char* ws = (char*)d_ws;

  size_t off = 0;
  auto alloc = [&](size_t n){ size_t o = off; off += (n + 255) & ~(size_t)255; return o; };
  float*          qk      = (float*)(ws + alloc(8192ull * 512 * 4));
  float*          vv      = (float*)(ws + alloc(8192ull * 512 * 4));
  float*          rot     = (float*)(ws + alloc(65536));
  unsigned short* buckets = (unsigned short*)(ws + alloc(16ull * TT * 2));
  unsigned int*   counts  = (unsigned int*)(ws + alloc(16ull * 512 * 4));
  unsigned int*   starts  = (unsigned int*)(ws + alloc(16ull * 512 * 4));
  unsigned short* s2pos   = (unsigned short*)(ws + alloc(16ull * TT * 2));
  unsigned short* pos2s   = (unsigned short*)(ws + alloc(16ull * TT * 2));
  float*          lse     = (float*)(ws + alloc(16ull * TT * 4));
  float*          wgt     = (float*)(ws + alloc(16ull * 8 * 4096 * 4));
  float*          attn    = (float*)(ws + alloc(16ull * 4096 * 64 * 4));
  size_t o_so = alloc(16ull * 8 * 4096 * 64 * 4);     // 134 MB
  bool fused = (off <= ws_size);
  float* so = (float*)(ws + o_so);

  hipMemsetAsync(counts, 0, 16ull * 512 * 4, stream);

  lsh_gemm_t<0, 320, false><<<dim3(128, 8), 256, 0, stream>>>(x, wqk, nullptr, qk);
  lsh_gemm_t<0, 320, true ><<<dim3(128, 8), 256, 0, stream>>>(x, wv,  nullptr, vv);
  lsh_gen_rot<<<dim3(64), 256, 0, stream>>>(rot);
  lsh_buckets3<<<dim3(16, 16, 8), 256, 0, stream>>>(qk, rot, buckets);
  lsh_hist<<<dim3(2048), 256, 0, stream>>>(buckets, counts);
  lsh_scan<<<dim3(16), 512, 0, stream>>>(counts, starts);
  lsh_rank<<<dim3(128), 256, 0, stream>>>(buckets, starts, s2pos, pos2s);
  if (fused){
    lsh_pv4<<<dim3(16 * 64, 8), 512, 0, stream>>>(qk, vv, s2pos, lse, so);
    lsh_comb<<<dim3(256), 256, 0, stream>>>(lse, pos2s, so, attn);
  } else {
    hipMemsetAsync(attn, 0, 16ull * 4096 * 64 * 4, stream);
    lsh_lse2<<<dim3(16 * 512), 256, 0, stream>>>(qk, s2pos, lse);
    lsh_wgt<<<dim3(256), 256, 0, stream>>>(lse, pos2s, wgt);
    for (int r = 0; r < 8; ++r)
      lsh_pv2<<<dim3(16 * 64), 256, 0, stream>>>(qk, vv, s2pos, lse, wgt, attn, r);
  }
  lsh_gemm_t<1, 320, true ><<<dim3(128, 8), 256, 0, stream>>>(attn, wout, bout, out);
}

// Round 21
// 761.400 us; speedup vs baseline: 1.1079x; 1.1079x over previous
//
#include <hip/hip_runtime.h>

// LSH (Reformer) attention. b=2, t=4096, e=512, h=8, d=64, n_hashes=8, bucket=64.
// All-f32. PASSING discrete recipe (round 13): partitionable threefry (o0^o1,
// ctr=(0,m)); no-FMA Horner erfinv + Eigen-plog; x@w_qk no-FMA mul/add kc=320;
// bucket einsum mul/add K=64. Round 21: revert pv to 256-thread fused (round-20
// 512-thr regressed: LDS still caps 2 blocks/CU, barriers costlier); XCD-aware
// block swizzle in pv3 (x = cc*16+bh so x%8==bh%8 -> same-bh blocks share an
// XCD L2; per-XCD working set 2bh x 2MB = 4MB = L2).

#define DI static __device__ __forceinline__

constexpr int Tn = 4096, En = 512, Dn = 64, NH = 8, TT = 32768;

// ---------------- threefry2x32 (key = [0,42]) ----------------
DI unsigned rotl32(unsigned v, int d){ return (v << d) | (v >> (32 - d)); }

DI void threefry_0_42(unsigned c0, unsigned c1, unsigned &o0, unsigned &o1){
  const unsigned k0 = 0u, k1 = 42u;
  const unsigned k2 = 0x1BD11BDAu ^ k0 ^ k1;
  unsigned x0 = c0 + k0, x1 = c1 + k1;
#define RND(rr) { x0 += x1; x1 = rotl32(x1, rr); x1 ^= x0; }
  RND(13) RND(15) RND(26) RND(6)  x0 += k1; x1 += k2 + 1u;
  RND(17) RND(29) RND(16) RND(24) x0 += k2; x1 += k0 + 2u;
  RND(13) RND(15) RND(26) RND(6)  x0 += k0; x1 += k1 + 3u;
  RND(17) RND(29) RND(16) RND(24) x0 += k1; x1 += k2 + 4u;
  RND(13) RND(15) RND(26) RND(6)  x0 += k2; x1 += k0 + 5u;
#undef RND
  o0 = x0; o1 = x1;
}

// ---------------- XLA CPU log.f32 rewrite = Eigen plog_float, NO fma ------------
DI float xla_logf(float xin){
  float x = fmaxf(xin, __uint_as_float(0x00800000u));
  unsigned ib = __float_as_uint(x);
  float e = (float)((int)(ib >> 23) - 126);
  x = __uint_as_float((ib & 0x807fffffu) | 0x3f000000u);
  float mask = (x < __uint_as_float(0x3F3504F3u)) ? 1.0f : 0.0f;
  float tmp = __fmul_rn(mask, x);
  x = __fsub_rn(x, 1.0f);
  e = __fsub_rn(e, mask);
  x = __fadd_rn(x, tmp);
  float x2 = __fmul_rn(x, x);
  float x3 = __fmul_rn(x2, x);
  float y  = __fadd_rn(__fmul_rn( 7.0376836292e-2f, x), -1.1514610310e-1f);
  float y1 = __fadd_rn(__fmul_rn(-1.2420140846e-1f, x),  1.4249322787e-1f);
  float y2 = __fadd_rn(__fmul_rn( 2.0000714765e-1f, x), -2.4999993993e-1f);
  y  = __fadd_rn(__fmul_rn(y,  x),  1.1676998740e-1f);
  y1 = __fadd_rn(__fmul_rn(y1, x), -1.6668057665e-1f);
  y2 = __fadd_rn(__fmul_rn(y2, x),  3.3333331174e-1f);
  y  = __fadd_rn(__fmul_rn(y, x3), y1);
  y  = __fadd_rn(__fmul_rn(y, x3), y2);
  y  = __fmul_rn(y, x3);
  y1 = __fmul_rn(e, -2.12194440e-4f);
  y2 = __fmul_rn(x2, 0.5f);
  y  = __fadd_rn(y, y1);
  x  = __fsub_rn(x, y2);
  y2 = __fmul_rn(e, 0.693359375f);
  x  = __fadd_rn(x, y);
  x  = __fadd_rn(x, y2);
  return x;
}

DI float xla_log1pf(float a){
  float fs = __fmul_rn(__fadd_rn(__fmul_rn(-0.5f, a), 1.0f), a);
  float fl = xla_logf(__fadd_rn(a, 1.0f));
  return (fabsf(a) < 1e-4f) ? fs : fl;
}

DI float bits_to_normal(unsigned bits){
  unsigned ub = (bits >> 9) | 0x3f800000u;
  float f = __fsub_rn(__uint_as_float(ub), 1.0f);
  const float lo = __uint_as_float(0xBF7FFFFFu);
  float x = __fadd_rn(__fmul_rn(f, 2.0f), lo);
  x = fmaxf(lo, x);
  float xx = __fmul_rn(x, x);
  float w = -xla_log1pf(-xx);
  float p;
  if (w < 5.0f){
    w = __fsub_rn(w, 2.5f);
    p = 2.81022636e-08f;
    p = __fadd_rn( 3.43273939e-07f, __fmul_rn(p, w));
    p = __fadd_rn(-3.5233877e-06f,  __fmul_rn(p, w));
    p = __fadd_rn(-4.39150654e-06f, __fmul_rn(p, w));
    p = __fadd_rn( 0.00021858087f,  __fmul_rn(p, w));
    p = __fadd_rn(-0.00125372503f,  __fmul_rn(p, w));
    p = __fadd_rn(-0.00417768164f,  __fmul_rn(p, w));
    p = __fadd_rn( 0.246640727f,    __fmul_rn(p, w));
    p = __fadd_rn( 1.50140941f,     __fmul_rn(p, w));
  } else {
    w = __fsub_rn(__fsqrt_rn(w), 3.0f);
    p = -0.000200214257f;
    p = __fadd_rn( 0.000100950558f, __fmul_rn(p, w));
    p = __fadd_rn( 0.00134934322f,  __fmul_rn(p, w));
    p = __fadd_rn(-0.00367342844f,  __fmul_rn(p, w));
    p = __fadd_rn( 0.00573950773f,  __fmul_rn(p, w));
    p = __fadd_rn(-0.0076224613f,   __fmul_rn(p, w));
    p = __fadd_rn( 0.00943887047f,  __fmul_rn(p, w));
    p = __fadd_rn( 1.00167406f,     __fmul_rn(p, w));
    p = __fadd_rn( 2.83297682f,     __fmul_rn(p, w));
  }
  float e = __fmul_rn(p, x);
  return __fmul_rn(__uint_as_float(0x3FB504F3u), e);
}

__global__ __launch_bounds__(256) void lsh_gen_rot(float* __restrict__ rot){
  int m = blockIdx.x * 256 + threadIdx.x;               // 0..16383
  unsigned o0, o1;
  threefry_0_42(0u, (unsigned)m, o0, o1);
  rot[m] = bits_to_normal(o0 ^ o1);
}

// ---------------- GEMM [8192x512]@[512x512], 64x64 tile, A+W in LDS -------------
template<int MODE, int KC, bool FMA>
__global__ __launch_bounds__(256) void lsh_gemm_t(const float* __restrict__ A,
                                                  const float* __restrict__ W,
                                                  const float* __restrict__ bias,
                                                  float* __restrict__ out){
  __shared__ float as[32][68];
  __shared__ float wsm[32][68];
  int rb = blockIdx.x, cb = blockIdx.y;
  int tid = threadIdx.x;
  int tr = (tid >> 4) << 2, tc = (tid & 15) << 2;
  float acc[4][4], tot[4][4];
#pragma unroll
  for (int i = 0; i < 4; ++i)
#pragma unroll
    for (int j = 0; j < 4; ++j){ acc[i][j] = 0.f; tot[i][j] = 0.f; }
  for (int k0 = 0; k0 < 512; k0 += 32){
    __syncthreads();
    for (int idx = tid; idx < 2048; idx += 256){
      int kk = idx & 31, r = idx >> 5;
      int row = rb * 64 + r, k = k0 + kk;
      float val;
      if (MODE == 0){
        val = A[(size_t)row * 512 + k];
      } else {
        int b = row >> 12, t = row & 4095, h = k >> 6, dd = k & 63;
        val = A[(((size_t)(b * 8 + h) * 4096) + t) * 64 + dd];
      }
      as[kk][r] = val;
    }
    for (int idx = tid; idx < 2048; idx += 256){
      int c = idx & 63, kk = idx >> 6;
      wsm[kk][c] = W[(size_t)(k0 + kk) * 512 + cb * 64 + c];
    }
    __syncthreads();
#pragma unroll
    for (int kk = 0; kk < 32; ++kk){
      int k = k0 + kk;
      if (!FMA && k && (k % KC) == 0){
#pragma unroll
        for (int i = 0; i < 4; ++i)
#pragma unroll
          for (int j = 0; j < 4; ++j){ tot[i][j] = __fadd_rn(tot[i][j], acc[i][j]); acc[i][j] = 0.f; }
      }
      float4 av = *(const float4*)&as[kk][tr];
      float4 wv = *(const float4*)&wsm[kk][tc];
      float ae[4] = {av.x, av.y, av.z, av.w};
      float we[4] = {wv.x, wv.y, wv.z, wv.w};
#pragma unroll
      for (int i = 0; i < 4; ++i)
#pragma unroll
        for (int j = 0; j < 4; ++j){
          if (FMA) acc[i][j] = fmaf(ae[i], we[j], acc[i][j]);
          else     acc[i][j] = __fadd_rn(acc[i][j], __fmul_rn(ae[i], we[j]));
        }
    }
  }
#pragma unroll
  for (int i = 0; i < 4; ++i){
#pragma unroll
    for (int j = 0; j < 4; ++j){
      float o = FMA ? acc[i][j] : __fadd_rn(tot[i][j], acc[i][j]);
      int col = cb * 64 + tc + j;
      if (MODE == 1) o += bias[col];
      out[(size_t)(rb * 64 + tr + i) * 512 + col] = o;
    }
  }
}

// ---------------- buckets: one round per block (grid z = 8) ----------------
__global__ __launch_bounds__(256) void lsh_buckets3(const float* __restrict__ qk,
                                                    const float* __restrict__ rot,
                                                    unsigned short* __restrict__ buckets){
  int bh = blockIdx.x, tile = blockIdx.y, r = blockIdx.z;
  int b = bh >> 3, h = bh & 7;
  int t = tile * 256 + threadIdx.x;
  __shared__ float rl[2048];
  float q[64];
  const float* qrow = qk + ((size_t)(b * Tn + t) * En + h * Dn);
#pragma unroll
  for (int f4 = 0; f4 < 16; ++f4){
    float4 v = *(const float4*)&qrow[f4 * 4];
    q[f4*4+0] = v.x; q[f4*4+1] = v.y; q[f4*4+2] = v.z; q[f4*4+3] = v.w;
  }
  for (int idx = threadIdx.x; idx < 2048; idx += 256)
    rl[idx] = rot[(idx >> 5) * 256 + r * 32 + (idx & 31)];
  __syncthreads();
  float acc[32];
#pragma unroll
  for (int i = 0; i < 32; ++i) acc[i] = 0.f;
#pragma unroll
  for (int f = 0; f < 64; ++f){
    float qf = q[f];
#pragma unroll
    for (int i = 0; i < 32; ++i) acc[i] = __fadd_rn(acc[i], __fmul_rn(qf, rl[f * 32 + i]));
  }
  float best = acc[0]; int bi = 0;
#pragma unroll
  for (int i = 1; i < 32; ++i) if (acc[i] > best){ best = acc[i]; bi = i; }
#pragma unroll
  for (int i = 0; i < 32; ++i){ float nv = -acc[i]; if (nv > best){ best = nv; bi = 32 + i; } }
  buckets[(size_t)bh * TT + r * Tn + t] = (unsigned short)(r * 64 + bi);
}

// ---------------- counting sort ----------------
__global__ __launch_bounds__(256) void lsh_hist(const unsigned short* __restrict__ buckets,
                                                unsigned int* __restrict__ counts){
  int idx = blockIdx.x * 256 + threadIdx.x;
  int bh = idx >> 15;
  atomicAdd(&counts[bh * 512 + buckets[idx]], 1u);
}

__global__ __launch_bounds__(512) void lsh_scan(const unsigned int* __restrict__ counts,
                                                unsigned int* __restrict__ starts){
  __shared__ unsigned int s[512];
  int bh = blockIdx.x, tid = threadIdx.x;
  unsigned int v = counts[bh * 512 + tid];
  s[tid] = v; __syncthreads();
  for (int off = 1; off < 512; off <<= 1){
    unsigned int add = (tid >= off) ? s[tid - off] : 0u;
    __syncthreads();
    s[tid] += add;
    __syncthreads();
  }
  starts[bh * 512 + tid] = s[tid] - v;
}

__global__ __launch_bounds__(256) void lsh_rank(const unsigned short* __restrict__ buckets,
                                                const unsigned int* __restrict__ starts,
                                                unsigned short* __restrict__ s2pos,
                                                unsigned short* __restrict__ pos2s){
  int bh = blockIdx.x >> 3, r = blockIdx.x & 7;
  __shared__ unsigned char lb[4096];
  __shared__ unsigned short cnt[64][4];
  const unsigned short* bsrc = buckets + (size_t)bh * TT + r * Tn;
  for (int t = threadIdx.x; t < 4096; t += 256) lb[t] = (unsigned char)(bsrc[t] - r * 64);
  __syncthreads();
  int b = threadIdx.x & 63, q = threadIdx.x >> 6;
  int c = 0;
  for (int t = q * 1024; t < (q + 1) * 1024; ++t) c += (lb[t] == b);
  cnt[b][q] = (unsigned short)c;
  __syncthreads();
  int off = 0;
  for (int q2 = 0; q2 < q; ++q2) off += cnt[b][q2];
  unsigned int run = starts[bh * 512 + r * 64 + b] + off;
  unsigned short* s2p = s2pos + (size_t)bh * TT;
  unsigned short* p2s = pos2s + (size_t)bh * TT + r * Tn;
  for (int t = q * 1024; t < (q + 1) * 1024; ++t){
    if (lb[t] == b){ s2p[run] = (unsigned short)t; p2s[t] = (unsigned short)run; run++; }
  }
}

#define KSTR 68
#define SWZ(row) ((((row) >> 3) & 7) << 2)

// ---------------- staging helper: 128 slot rows -> normalized swizzled LDS ------
DI void stage_rows(const float* __restrict__ qk, const unsigned short* __restrict__ s2pos,
                   int bh, int b, int h, int c, int cprev,
                   float* kbuf, float* den, unsigned short* kt){
  int j = threadIdx.x >> 1, half = threadIdx.x & 1;
  int slot = (j < 64) ? (c * 64 + j) : (cprev * 64 + (j - 64));
  int t = s2pos[(size_t)bh * TT + slot];
  const float* row = qk + ((size_t)(b * Tn + t) * En + h * Dn);
  int sw = SWZ(j);
  float tmp[32]; float ss = 0.f;
#pragma unroll
  for (int dd = 0; dd < 32; ++dd){ float xv = row[half * 32 + dd]; tmp[dd] = xv; ss = fmaf(xv, xv, ss); }
  ss += __shfl_xor(ss, 1);
  float dn = sqrtf(ss) + 1e-6f;
#pragma unroll
  for (int d4 = 0; d4 < 8; ++d4){
    float4 o; o.x = tmp[4*d4] / dn; o.y = tmp[4*d4+1] / dn; o.z = tmp[4*d4+2] / dn; o.w = tmp[4*d4+3] / dn;
    *(float4*)&kbuf[j * KSTR + ((half * 32 + 4 * d4) ^ sw)] = o;
  }
  if (!half){ den[j] = dn; kt[j] = (unsigned short)t; }
}

// ---------------- register-tiled dots: thread = 4q x 8k (swizzled reads) --------
DI void dots_tile(const float* kbuf, const float* den, const unsigned short* kt,
                  int a, int bb, float dots[4][8]){
  int swq = SWZ(4 * a);
  int swk = SWZ(8 * bb);
#pragma unroll
  for (int qq = 0; qq < 4; ++qq)
#pragma unroll
    for (int kk = 0; kk < 8; ++kk) dots[qq][kk] = 0.f;
#pragma unroll
  for (int d4 = 0; d4 < 16; ++d4){
    float4 qv[4], kv[8];
#pragma unroll
    for (int qq = 0; qq < 4; ++qq) qv[qq] = *(const float4*)&kbuf[(4*a+qq) * KSTR + ((d4 * 4) ^ swq)];
#pragma unroll
    for (int kk = 0; kk < 8; ++kk) kv[kk] = *(const float4*)&kbuf[(8*bb+kk) * KSTR + ((d4 * 4) ^ swk)];
#pragma unroll
    for (int qq = 0; qq < 4; ++qq)
#pragma unroll
      for (int kk = 0; kk < 8; ++kk){
        dots[qq][kk] = fmaf(qv[qq].x, kv[kk].x, dots[qq][kk]);
        dots[qq][kk] = fmaf(qv[qq].y, kv[kk].y, dots[qq][kk]);
        dots[qq][kk] = fmaf(qv[qq].z, kv[kk].z, dots[qq][kk]);
        dots[qq][kk] = fmaf(qv[qq].w, kv[kk].w, dots[qq][kk]);
      }
  }
#pragma unroll
  for (int qq = 0; qq < 4; ++qq){
    float sc = den[4*a+qq] * 0.125f;
    int qt = kt[4*a+qq];
#pragma unroll
    for (int kk = 0; kk < 8; ++kk){
      float v = dots[qq][kk] * sc;
      if ((int)kt[8*bb+kk] == qt) v = -1e5f;
      dots[qq][kk] = v;
    }
  }
}

// ---------------- pass 1: per-slot LSE (fallback path) ----------------
__global__ __launch_bounds__(256) void lsh_lse2(const float* __restrict__ qk,
                                                const unsigned short* __restrict__ s2pos,
                                                float* __restrict__ lse){
  int bh = blockIdx.x >> 9, c = blockIdx.x & 511;
  int b = bh >> 3, h = bh & 7;
  int cprev = (c + 511) & 511;
  __shared__ float kbuf[128 * KSTR];
  __shared__ float den[128];
  __shared__ unsigned short kt[128];
  __shared__ float red2[64][17];
  __shared__ float Marr[64];
  stage_rows(qk, s2pos, bh, b, h, c, cprev, kbuf, den, kt);
  __syncthreads();
  int a = threadIdx.x & 15, bb = threadIdx.x >> 4;
  float dots[4][8];
  dots_tile(kbuf, den, kt, a, bb, dots);
#pragma unroll
  for (int qq = 0; qq < 4; ++qq){
    float m = dots[qq][0];
#pragma unroll
    for (int kk = 1; kk < 8; ++kk) m = fmaxf(m, dots[qq][kk]);
    red2[4*a+qq][bb] = m;
  }
  __syncthreads();
  if (threadIdx.x < 64){
    float M = red2[threadIdx.x][0];
#pragma unroll
    for (int j = 1; j < 16; ++j) M = fmaxf(M, red2[threadIdx.x][j]);
    Marr[threadIdx.x] = M;
  }
  __syncthreads();
  float ssum[4];
#pragma unroll
  for (int qq = 0; qq < 4; ++qq){
    float M = Marr[4*a+qq];
    float s = 0.f;
#pragma unroll
    for (int kk = 0; kk < 8; ++kk) s += expf(dots[qq][kk] - M);
    ssum[qq] = s;
  }
  __syncthreads();
#pragma unroll
  for (int qq = 0; qq < 4; ++qq) red2[4*a+qq][bb] = ssum[qq];
  __syncthreads();
  if (threadIdx.x < 64){
    float S = 0.f;
#pragma unroll
    for (int j = 0; j < 16; ++j) S += red2[threadIdx.x][j];
    lse[(size_t)bh * TT + c * 64 + threadIdx.x] = Marr[threadIdx.x] + logf(S);
  }
}

// ---------------- per-(bh,t) round weights (fallback path) ----------------
__global__ __launch_bounds__(256) void lsh_wgt(const float* __restrict__ lse,
                                               const unsigned short* __restrict__ pos2s,
                                               float* __restrict__ wgt){
  int idx = blockIdx.x * 256 + threadIdx.x;
  int bh = idx >> 12, t = idx & 4095;
  float l[8];
#pragma unroll
  for (int r = 0; r < 8; ++r){
    int s = pos2s[(size_t)bh * TT + r * Tn + t];
    l[r] = lse[(size_t)bh * TT + s];
  }
  float M = l[0];
#pragma unroll
  for (int r = 1; r < 8; ++r) M = fmaxf(M, l[r]);
  float S = 0.f;
#pragma unroll
  for (int r = 0; r < 8; ++r) S += expf(l[r] - M);
  float L = M + logf(S);
#pragma unroll
  for (int r = 0; r < 8; ++r) wgt[(size_t)(bh * 8 + r) * Tn + t] = expf(l[r] - L);
}

// ---------------- fused pv: dots + in-block LSE + PV -> so, lse ----------------
// Block decode XCD-swizzled: x = cc*16 + bh so x%8 == bh%8 (same-bh -> same XCD L2).
__global__ __launch_bounds__(256) void lsh_pv3(const float* __restrict__ qk,
                                               const float* __restrict__ vv,
                                               const unsigned short* __restrict__ s2pos,
                                               float* __restrict__ lse,
                                               float* __restrict__ so){
  int r = blockIdx.y;
  int bh = blockIdx.x & 15, cc = blockIdx.x >> 4;
  int c = r * 64 + cc, cprev = (c + 511) & 511;
  int b = bh >> 3, h = bh & 7;
  __shared__ float kbuf[128 * KSTR];          // aliased later as P[64][132]
  __shared__ float vbuf[128 * KSTR];          // head aliased as reduce scratch
  __shared__ float den[128];
  __shared__ unsigned short kt[128];
  float (*red2)[17] = (float(*)[17])vbuf;     // [64][17]
  float* Marr = vbuf + 64 * 17;               // [64]
  stage_rows(qk, s2pos, bh, b, h, c, cprev, kbuf, den, kt);
  __syncthreads();
  int a = threadIdx.x & 15, bb = threadIdx.x >> 4;
  float dots[4][8];
  dots_tile(kbuf, den, kt, a, bb, dots);
  // ---- in-block LSE ----
#pragma unroll
  for (int qq = 0; qq < 4; ++qq){
    float m = dots[qq][0];
#pragma unroll
    for (int kk = 1; kk < 8; ++kk) m = fmaxf(m, dots[qq][kk]);
    red2[4*a+qq][bb] = m;
  }
  __syncthreads();
  if (threadIdx.x < 64){
    float M = red2[threadIdx.x][0];
#pragma unroll
    for (int j = 1; j < 16; ++j) M = fmaxf(M, red2[threadIdx.x][j]);
    Marr[threadIdx.x] = M;
  }
  __syncthreads();
  float ssum[4];
#pragma unroll
  for (int qq = 0; qq < 4; ++qq){
    float M = Marr[4*a+qq];
    float s = 0.f;
#pragma unroll
    for (int kk = 0; kk < 8; ++kk) s += expf(dots[qq][kk] - M);
    ssum[qq] = s;
  }
  __syncthreads();
#pragma unroll
  for (int qq = 0; qq < 4; ++qq) red2[4*a+qq][bb] = ssum[qq];
  __syncthreads();
  if (threadIdx.x < 64){
    float S = 0.f;
#pragma unroll
    for (int j = 0; j < 16; ++j) S += red2[threadIdx.x][j];
    float lv = Marr[threadIdx.x] + logf(S);
    lse[(size_t)bh * TT + c * 64 + threadIdx.x] = lv;
    Marr[threadIdx.x] = lv;                   // broadcast lse to all threads
  }
  __syncthreads();
  float lrow[4];
#pragma unroll
  for (int qq = 0; qq < 4; ++qq) lrow[qq] = Marr[4*a+qq];
#pragma unroll
  for (int qq = 0; qq < 4; ++qq)
#pragma unroll
    for (int kk = 0; kk < 8; ++kk) dots[qq][kk] = expf(dots[qq][kk] - lrow[qq]);
  __syncthreads();                            // reduce scratch reads done; K reads done
  // write P (swizzled) into kbuf alias; stage V (swizzled) into vbuf
  float* pb = kbuf;
  {
    int swp = SWZ(4 * a);
#pragma unroll
    for (int qq = 0; qq < 4; ++qq){
      *(float4*)&pb[(4*a+qq) * 132 + ((8*bb)     ^ swp)] = make_float4(dots[qq][0], dots[qq][1], dots[qq][2], dots[qq][3]);
      *(float4*)&pb[(4*a+qq) * 132 + ((8*bb + 4) ^ swp)] = make_float4(dots[qq][4], dots[qq][5], dots[qq][6], dots[qq][7]);
    }
  }
  {
    int j = threadIdx.x >> 1, half = threadIdx.x & 1;
    int t = kt[j];
    int sw = SWZ(j);
    const float* row = vv + ((size_t)(b * Tn + t) * En + h * Dn);
#pragma unroll
    for (int d4 = 0; d4 < 8; ++d4){
      float4 o;
      o.x = row[half*32 + 4*d4]; o.y = row[half*32 + 4*d4 + 1];
      o.z = row[half*32 + 4*d4 + 2]; o.w = row[half*32 + 4*d4 + 3];
      *(float4*)&vbuf[j * KSTR + ((half * 32 + 4 * d4) ^ sw)] = o;
    }
  }
  __syncthreads();
  int qg = threadIdx.x & 15, dg = threadIdx.x >> 4;
  float acc[4][4];
#pragma unroll
  for (int qq = 0; qq < 4; ++qq)
#pragma unroll
    for (int dd = 0; dd < 4; ++dd) acc[qq][dd] = 0.f;
  int swp = SWZ(4 * qg);
  for (int k4 = 0; k4 < 32; ++k4){
    int swv = SWZ(4 * k4);
    float4 pr[4], vr[4];
#pragma unroll
    for (int qq = 0; qq < 4; ++qq) pr[qq] = *(const float4*)&pb[(4*qg+qq) * 132 + ((k4 * 4) ^ swp)];
#pragma unroll
    for (int kk = 0; kk < 4; ++kk) vr[kk] = *(const float4*)&vbuf[(k4*4+kk) * KSTR + ((4*dg) ^ swv)];
#pragma unroll
    for (int kk = 0; kk < 4; ++kk){
#pragma unroll
      for (int qq = 0; qq < 4; ++qq){
        float p = (kk == 0) ? pr[qq].x : (kk == 1) ? pr[qq].y : (kk == 2) ? pr[qq].z : pr[qq].w;
        acc[qq][0] = fmaf(p, vr[kk].x, acc[qq][0]);
        acc[qq][1] = fmaf(p, vr[kk].y, acc[qq][1]);
        acc[qq][2] = fmaf(p, vr[kk].z, acc[qq][2]);
        acc[qq][3] = fmaf(p, vr[kk].w, acc[qq][3]);
      }
    }
  }
#pragma unroll
  for (int qq = 0; qq < 4; ++qq){
    int i = 4*qg + qq;
    int qt = kt[i];
    float* srow = so + (((size_t)(bh * 8 + r) * Tn) + qt) * Dn + 4*dg;
    *(float4*)srow = make_float4(acc[qq][0], acc[qq][1], acc[qq][2], acc[qq][3]);
  }
}

// ---------------- combine: attn[bh][t] = sum_r exp(lse_r - LSE) * so[r] --------
__global__ __launch_bounds__(256) void lsh_comb(const float* __restrict__ lse,
                                                const unsigned short* __restrict__ pos2s,
                                                const float* __restrict__ so,
                                                float* __restrict__ attn){
  int idx = blockIdx.x * 256 + threadIdx.x;   // 16*4096
  int bh = idx >> 12, t = idx & 4095;
  float l[8];
#pragma unroll
  for (int r = 0; r < 8; ++r){
    int s = pos2s[(size_t)bh * TT + r * Tn + t];
    l[r] = lse[(size_t)bh * TT + s];
  }
  float M = l[0];
#pragma unroll
  for (int r = 1; r < 8; ++r) M = fmaxf(M, l[r]);
  float S = 0.f;
#pragma unroll
  for (int r = 0; r < 8; ++r) S += expf(l[r] - M);
  float L = M + logf(S);
  float acc[64];
#pragma unroll
  for (int d = 0; d < 64; ++d) acc[d] = 0.f;
  for (int r = 0; r < 8; ++r){
    float w = expf(l[r] - L);
    const float* srow = so + (((size_t)(bh * 8 + r) * Tn) + t) * Dn;
#pragma unroll
    for (int d4 = 0; d4 < 16; ++d4){
      float4 v = *(const float4*)&srow[d4 * 4];
      acc[4*d4+0] = fmaf(w, v.x, acc[4*d4+0]);
      acc[4*d4+1] = fmaf(w, v.y, acc[4*d4+1]);
      acc[4*d4+2] = fmaf(w, v.z, acc[4*d4+2]);
      acc[4*d4+3] = fmaf(w, v.w, acc[4*d4+3]);
    }
  }
  float* arow = attn + ((size_t)(bh * Tn + t)) * Dn;
#pragma unroll
  for (int d4 = 0; d4 < 16; ++d4)
    *(float4*)&arow[d4 * 4] = make_float4(acc[4*d4], acc[4*d4+1], acc[4*d4+2], acc[4*d4+3]);
}

// ---------------- pass 2 (fallback): probs, PV, direct += ----------------
__global__ __launch_bounds__(256) void lsh_pv2(const float* __restrict__ qk,
                                               const float* __restrict__ vv,
                                               const unsigned short* __restrict__ s2pos,
                                               const float* __restrict__ lse,
                                               const float* __restrict__ wgt,
                                               float* __restrict__ attn, int r){
  int bh = blockIdx.x >> 6, cc = blockIdx.x & 63;
  int c = r * 64 + cc, cprev = (c + 511) & 511;
  int b = bh >> 3, h = bh & 7;
  __shared__ float kbuf[128 * KSTR];
  __shared__ float vbuf[128 * KSTR];
  __shared__ float den[128];
  __shared__ unsigned short kt[128];
  stage_rows(qk, s2pos, bh, b, h, c, cprev, kbuf, den, kt);
  __syncthreads();
  int a = threadIdx.x & 15, bb = threadIdx.x >> 4;
  float dots[4][8];
  dots_tile(kbuf, den, kt, a, bb, dots);
  float lrow[4];
#pragma unroll
  for (int qq = 0; qq < 4; ++qq) lrow[qq] = lse[(size_t)bh * TT + c * 64 + 4*a+qq];
#pragma unroll
  for (int qq = 0; qq < 4; ++qq)
#pragma unroll
    for (int kk = 0; kk < 8; ++kk) dots[qq][kk] = expf(dots[qq][kk] - lrow[qq]);
  __syncthreads();
  float* pb = kbuf;
  {
    int swp = SWZ(4 * a);
#pragma unroll
    for (int qq = 0; qq < 4; ++qq){
      *(float4*)&pb[(4*a+qq) * 132 + ((8*bb)     ^ swp)] = make_float4(dots[qq][0], dots[qq][1], dots[qq][2], dots[qq][3]);
      *(float4*)&pb[(4*a+qq) * 132 + ((8*bb + 4) ^ swp)] = make_float4(dots[qq][4], dots[qq][5], dots[qq][6], dots[qq][7]);
    }
  }
  {
    int j = threadIdx.x >> 1, half = threadIdx.x & 1;
    int t = kt[j];
    int sw = SWZ(j);
    const float* row = vv + ((size_t)(b * Tn + t) * En + h * Dn);
#pragma unroll
    for (int d4 = 0; d4 < 8; ++d4){
      float4 o;
      o.x = row[half*32 + 4*d4]; o.y = row[half*32 + 4*d4 + 1];
      o.z = row[half*32 + 4*d4 + 2]; o.w = row[half*32 + 4*d4 + 3];
      *(float4*)&vbuf[j * KSTR + ((half * 32 + 4 * d4) ^ sw)] = o;
    }
  }
  __syncthreads();
  int qg = threadIdx.x & 15, dg = threadIdx.x >> 4;
  float acc[4][4];
#pragma unroll
  for (int qq = 0; qq < 4; ++qq)
#pragma unroll
    for (int dd = 0; dd < 4; ++dd) acc[qq][dd] = 0.f;
  int swp = SWZ(4 * qg);
  for (int k4 = 0; k4 < 32; ++k4){
    int swv = SWZ(4 * k4);
    float4 pr[4], vr[4];
#pragma unroll
    for (int qq = 0; qq < 4; ++qq) pr[qq] = *(const float4*)&pb[(4*qg+qq) * 132 + ((k4 * 4) ^ swp)];
#pragma unroll
    for (int kk = 0; kk < 4; ++kk) vr[kk] = *(const float4*)&vbuf[(k4*4+kk) * KSTR + ((4*dg) ^ swv)];
#pragma unroll
    for (int kk = 0; kk < 4; ++kk){
#pragma unroll
      for (int qq = 0; qq < 4; ++qq){
        float p = (kk == 0) ? pr[qq].x : (kk == 1) ? pr[qq].y : (kk == 2) ? pr[qq].z : pr[qq].w;
        acc[qq][0] = fmaf(p, vr[kk].x, acc[qq][0]);
        acc[qq][1] = fmaf(p, vr[kk].y, acc[qq][1]);
        acc[qq][2] = fmaf(p, vr[kk].z, acc[qq][2]);
        acc[qq][3] = fmaf(p, vr[kk].w, acc[qq][3]);
      }
    }
  }
#pragma unroll
  for (int qq = 0; qq < 4; ++qq){
    int i = 4*qg + qq;
    int qt = kt[i];
    float w = wgt[(size_t)(bh * 8 + r) * Tn + qt];
    float* arow = attn + ((size_t)(bh * Tn + qt)) * Dn + 4*dg;
    float4 old = *(float4*)arow;
    old.x += w * acc[qq][0]; old.y += w * acc[qq][1];
    old.z += w * acc[qq][2]; old.w += w * acc[qq][3];
    *(float4*)arow = old;
  }
}

// ---------------- host ----------------
extern "C" void kernel_launch(void* const* d_in, const int* in_sizes, int n_in,
                              void* d_out, int out_size, void* d_ws, size_t ws_size,
                              hipStream_t stream){
  (void)in_sizes; (void)n_in; (void)out_size;
  const float* x    = (const float*)d_in[0];
  const float* wqk  = (const float*)d_in[1];
  const float* wv   = (const float*)d_in[2];
  const float* wout = (const float*)d_in[3];
  const float* bout = (const float*)d_in[4];
  float* out = (float*)d_out;
  char* ws = (char*)d_ws;

  size_t off = 0;
  auto alloc = [&](size_t n){ size_t o = off; off += (n + 255) & ~(size_t)255; return o; };
  float*          qk      = (float*)(ws + alloc(8192ull * 512 * 4));
  float*          vv      = (float*)(ws + alloc(8192ull * 512 * 4));
  float*          rot     = (float*)(ws + alloc(65536));
  unsigned short* buckets = (unsigned short*)(ws + alloc(16ull * TT * 2));
  unsigned int*   counts  = (unsigned int*)(ws + alloc(16ull * 512 * 4));
  unsigned int*   starts  = (unsigned int*)(ws + alloc(16ull * 512 * 4));
  unsigned short* s2pos   = (unsigned short*)(ws + alloc(16ull * TT * 2));
  unsigned short* pos2s   = (unsigned short*)(ws + alloc(16ull * TT * 2));
  float*          lse     = (float*)(ws + alloc(16ull * TT * 4));
  float*          wgt     = (float*)(ws + alloc(16ull * 8 * 4096 * 4));
  float*          attn    = (float*)(ws + alloc(16ull * 4096 * 64 * 4));
  size_t o_so = alloc(16ull * 8 * 4096 * 64 * 4);     // 134 MB
  bool fused = (off <= ws_size);
  float* so = (float*)(ws + o_so);

  hipMemsetAsync(counts, 0, 16ull * 512 * 4, stream);

  lsh_gemm_t<0, 320, false><<<dim3(128, 8), 256, 0, stream>>>(x, wqk, nullptr, qk);
  lsh_gemm_t<0, 320, true ><<<dim3(128, 8), 256, 0, stream>>>(x, wv,  nullptr, vv);
  lsh_gen_rot<<<dim3(64), 256, 0, stream>>>(rot);
  lsh_buckets3<<<dim3(16, 16, 8), 256, 0, stream>>>(qk, rot, buckets);
  lsh_hist<<<dim3(2048), 256, 0, stream>>>(buckets, counts);
  lsh_scan<<<dim3(16), 512, 0, stream>>>(counts, starts);
  lsh_rank<<<dim3(128), 256, 0, stream>>>(buckets, starts, s2pos, pos2s);
  if (fused){
    lsh_pv3<<<dim3(16 * 64, 8), 256, 0, stream>>>(qk, vv, s2pos, lse, so);
    lsh_comb<<<dim3(256), 256, 0, stream>>>(lse, pos2s, so, attn);
  } else {
    hipMemsetAsync(attn, 0, 16ull * 4096 * 64 * 4, stream);
    lsh_lse2<<<dim3(16 * 512), 256, 0, stream>>>(qk, s2pos, lse);
    lsh_wgt<<<dim3(256), 256, 0, stream>>>(lse, pos2s, wgt);
    for (int r = 0; r < 8; ++r)
      lsh_pv2<<<dim3(16 * 64), 256, 0, stream>>>(qk, vv, s2pos, lse, wgt, attn, r);
  }
  lsh_gemm_t<1, 320, true ><<<dim3(128, 8), 256, 0, stream>>>(attn, wout, bout, out);
}

// Round 22
// 719.262 us; speedup vs baseline: 1.1729x; 1.0586x over previous
//
#include <hip/hip_runtime.h>

// LSH (Reformer) attention. b=2, t=4096, e=512, h=8, d=64, n_hashes=8, bucket=64.
// All-f32. PASSING discrete recipe (round 13): partitionable threefry (o0^o1,
// ctr=(0,m)); no-FMA Horner erfinv + Eigen-plog; x@w_qk no-FMA mul/add kc=320;
// bucket einsum mul/add K=64. Round 22: pv3 LDS diet -> half-size V buffer,
// PV in two k-halves (same k-ascending order, bitwise identical). LDS 69->53KB
// => 3 blocks/CU (was 2), occupancy +50%. Keeps XCD swizzle (FETCH 263->103MB).

#define DI static __device__ __forceinline__

constexpr int Tn = 4096, En = 512, Dn = 64, NH = 8, TT = 32768;

// ---------------- threefry2x32 (key = [0,42]) ----------------
DI unsigned rotl32(unsigned v, int d){ return (v << d) | (v >> (32 - d)); }

DI void threefry_0_42(unsigned c0, unsigned c1, unsigned &o0, unsigned &o1){
  const unsigned k0 = 0u, k1 = 42u;
  const unsigned k2 = 0x1BD11BDAu ^ k0 ^ k1;
  unsigned x0 = c0 + k0, x1 = c1 + k1;
#define RND(rr) { x0 += x1; x1 = rotl32(x1, rr); x1 ^= x0; }
  RND(13) RND(15) RND(26) RND(6)  x0 += k1; x1 += k2 + 1u;
  RND(17) RND(29) RND(16) RND(24) x0 += k2; x1 += k0 + 2u;
  RND(13) RND(15) RND(26) RND(6)  x0 += k0; x1 += k1 + 3u;
  RND(17) RND(29) RND(16) RND(24) x0 += k1; x1 += k2 + 4u;
  RND(13) RND(15) RND(26) RND(6)  x0 += k2; x1 += k0 + 5u;
#undef RND
  o0 = x0; o1 = x1;
}

// ---------------- XLA CPU log.f32 rewrite = Eigen plog_float, NO fma ------------
DI float xla_logf(float xin){
  float x = fmaxf(xin, __uint_as_float(0x00800000u));
  unsigned ib = __float_as_uint(x);
  float e = (float)((int)(ib >> 23) - 126);
  x = __uint_as_float((ib & 0x807fffffu) | 0x3f000000u);
  float mask = (x < __uint_as_float(0x3F3504F3u)) ? 1.0f : 0.0f;
  float tmp = __fmul_rn(mask, x);
  x = __fsub_rn(x, 1.0f);
  e = __fsub_rn(e, mask);
  x = __fadd_rn(x, tmp);
  float x2 = __fmul_rn(x, x);
  float x3 = __fmul_rn(x2, x);
  float y  = __fadd_rn(__fmul_rn( 7.0376836292e-2f, x), -1.1514610310e-1f);
  float y1 = __fadd_rn(__fmul_rn(-1.2420140846e-1f, x),  1.4249322787e-1f);
  float y2 = __fadd_rn(__fmul_rn( 2.0000714765e-1f, x), -2.4999993993e-1f);
  y  = __fadd_rn(__fmul_rn(y,  x),  1.1676998740e-1f);
  y1 = __fadd_rn(__fmul_rn(y1, x), -1.6668057665e-1f);
  y2 = __fadd_rn(__fmul_rn(y2, x),  3.3333331174e-1f);
  y  = __fadd_rn(__fmul_rn(y, x3), y1);
  y  = __fadd_rn(__fmul_rn(y, x3), y2);
  y  = __fmul_rn(y, x3);
  y1 = __fmul_rn(e, -2.12194440e-4f);
  y2 = __fmul_rn(x2, 0.5f);
  y  = __fadd_rn(y, y1);
  x  = __fsub_rn(x, y2);
  y2 = __fmul_rn(e, 0.693359375f);
  x  = __fadd_rn(x, y);
  x  = __fadd_rn(x, y2);
  return x;
}

DI float xla_log1pf(float a){
  float fs = __fmul_rn(__fadd_rn(__fmul_rn(-0.5f, a), 1.0f), a);
  float fl = xla_logf(__fadd_rn(a, 1.0f));
  return (fabsf(a) < 1e-4f) ? fs : fl;
}

DI float bits_to_normal(unsigned bits){
  unsigned ub = (bits >> 9) | 0x3f800000u;
  float f = __fsub_rn(__uint_as_float(ub), 1.0f);
  const float lo = __uint_as_float(0xBF7FFFFFu);
  float x = __fadd_rn(__fmul_rn(f, 2.0f), lo);
  x = fmaxf(lo, x);
  float xx = __fmul_rn(x, x);
  float w = -xla_log1pf(-xx);
  float p;
  if (w < 5.0f){
    w = __fsub_rn(w, 2.5f);
    p = 2.81022636e-08f;
    p = __fadd_rn( 3.43273939e-07f, __fmul_rn(p, w));
    p = __fadd_rn(-3.5233877e-06f,  __fmul_rn(p, w));
    p = __fadd_rn(-4.39150654e-06f, __fmul_rn(p, w));
    p = __fadd_rn( 0.00021858087f,  __fmul_rn(p, w));
    p = __fadd_rn(-0.00125372503f,  __fmul_rn(p, w));
    p = __fadd_rn(-0.00417768164f,  __fmul_rn(p, w));
    p = __fadd_rn( 0.246640727f,    __fmul_rn(p, w));
    p = __fadd_rn( 1.50140941f,     __fmul_rn(p, w));
  } else {
    w = __fsub_rn(__fsqrt_rn(w), 3.0f);
    p = -0.000200214257f;
    p = __fadd_rn( 0.000100950558f, __fmul_rn(p, w));
    p = __fadd_rn( 0.00134934322f,  __fmul_rn(p, w));
    p = __fadd_rn(-0.00367342844f,  __fmul_rn(p, w));
    p = __fadd_rn( 0.00573950773f,  __fmul_rn(p, w));
    p = __fadd_rn(-0.0076224613f,   __fmul_rn(p, w));
    p = __fadd_rn( 0.00943887047f,  __fmul_rn(p, w));
    p = __fadd_rn( 1.00167406f,     __fmul_rn(p, w));
    p = __fadd_rn( 2.83297682f,     __fmul_rn(p, w));
  }
  float e = __fmul_rn(p, x);
  return __fmul_rn(__uint_as_float(0x3FB504F3u), e);
}

__global__ __launch_bounds__(256) void lsh_gen_rot(float* __restrict__ rot){
  int m = blockIdx.x * 256 + threadIdx.x;               // 0..16383
  unsigned o0, o1;
  threefry_0_42(0u, (unsigned)m, o0, o1);
  rot[m] = bits_to_normal(o0 ^ o1);
}

// ---------------- GEMM [8192x512]@[512x512], 64x64 tile, A+W in LDS -------------
template<int MODE, int KC, bool FMA>
__global__ __launch_bounds__(256) void lsh_gemm_t(const float* __restrict__ A,
                                                  const float* __restrict__ W,
                                                  const float* __restrict__ bias,
                                                  float* __restrict__ out){
  __shared__ float as[32][68];
  __shared__ float wsm[32][68];
  int rb = blockIdx.x, cb = blockIdx.y;
  int tid = threadIdx.x;
  int tr = (tid >> 4) << 2, tc = (tid & 15) << 2;
  float acc[4][4], tot[4][4];
#pragma unroll
  for (int i = 0; i < 4; ++i)
#pragma unroll
    for (int j = 0; j < 4; ++j){ acc[i][j] = 0.f; tot[i][j] = 0.f; }
  for (int k0 = 0; k0 < 512; k0 += 32){
    __syncthreads();
    for (int idx = tid; idx < 2048; idx += 256){
      int kk = idx & 31, r = idx >> 5;
      int row = rb * 64 + r, k = k0 + kk;
      float val;
      if (MODE == 0){
        val = A[(size_t)row * 512 + k];
      } else {
        int b = row >> 12, t = row & 4095, h = k >> 6, dd = k & 63;
        val = A[(((size_t)(b * 8 + h) * 4096) + t) * 64 + dd];
      }
      as[kk][r] = val;
    }
    for (int idx = tid; idx < 2048; idx += 256){
      int c = idx & 63, kk = idx >> 6;
      wsm[kk][c] = W[(size_t)(k0 + kk) * 512 + cb * 64 + c];
    }
    __syncthreads();
#pragma unroll
    for (int kk = 0; kk < 32; ++kk){
      int k = k0 + kk;
      if (!FMA && k && (k % KC) == 0){
#pragma unroll
        for (int i = 0; i < 4; ++i)
#pragma unroll
          for (int j = 0; j < 4; ++j){ tot[i][j] = __fadd_rn(tot[i][j], acc[i][j]); acc[i][j] = 0.f; }
      }
      float4 av = *(const float4*)&as[kk][tr];
      float4 wv = *(const float4*)&wsm[kk][tc];
      float ae[4] = {av.x, av.y, av.z, av.w};
      float we[4] = {wv.x, wv.y, wv.z, wv.w};
#pragma unroll
      for (int i = 0; i < 4; ++i)
#pragma unroll
        for (int j = 0; j < 4; ++j){
          if (FMA) acc[i][j] = fmaf(ae[i], we[j], acc[i][j]);
          else     acc[i][j] = __fadd_rn(acc[i][j], __fmul_rn(ae[i], we[j]));
        }
    }
  }
#pragma unroll
  for (int i = 0; i < 4; ++i){
#pragma unroll
    for (int j = 0; j < 4; ++j){
      float o = FMA ? acc[i][j] : __fadd_rn(tot[i][j], acc[i][j]);
      int col = cb * 64 + tc + j;
      if (MODE == 1) o += bias[col];
      out[(size_t)(rb * 64 + tr + i) * 512 + col] = o;
    }
  }
}

// ---------------- buckets: one round per block (grid z = 8) ----------------
__global__ __launch_bounds__(256) void lsh_buckets3(const float* __restrict__ qk,
                                                    const float* __restrict__ rot,
                                                    unsigned short* __restrict__ buckets){
  int bh = blockIdx.x, tile = blockIdx.y, r = blockIdx.z;
  int b = bh >> 3, h = bh & 7;
  int t = tile * 256 + threadIdx.x;
  __shared__ float rl[2048];
  float q[64];
  const float* qrow = qk + ((size_t)(b * Tn + t) * En + h * Dn);
#pragma unroll
  for (int f4 = 0; f4 < 16; ++f4){
    float4 v = *(const float4*)&qrow[f4 * 4];
    q[f4*4+0] = v.x; q[f4*4+1] = v.y; q[f4*4+2] = v.z; q[f4*4+3] = v.w;
  }
  for (int idx = threadIdx.x; idx < 2048; idx += 256)
    rl[idx] = rot[(idx >> 5) * 256 + r * 32 + (idx & 31)];
  __syncthreads();
  float acc[32];
#pragma unroll
  for (int i = 0; i < 32; ++i) acc[i] = 0.f;
#pragma unroll
  for (int f = 0; f < 64; ++f){
    float qf = q[f];
#pragma unroll
    for (int i = 0; i < 32; ++i) acc[i] = __fadd_rn(acc[i], __fmul_rn(qf, rl[f * 32 + i]));
  }
  float best = acc[0]; int bi = 0;
#pragma unroll
  for (int i = 1; i < 32; ++i) if (acc[i] > best){ best = acc[i]; bi = i; }
#pragma unroll
  for (int i = 0; i < 32; ++i){ float nv = -acc[i]; if (nv > best){ best = nv; bi = 32 + i; } }
  buckets[(size_t)bh * TT + r * Tn + t] = (unsigned short)(r * 64 + bi);
}

// ---------------- counting sort ----------------
__global__ __launch_bounds__(256) void lsh_hist(const unsigned short* __restrict__ buckets,
                                                unsigned int* __restrict__ counts){
  int idx = blockIdx.x * 256 + threadIdx.x;
  int bh = idx >> 15;
  atomicAdd(&counts[bh * 512 + buckets[idx]], 1u);
}

__global__ __launch_bounds__(512) void lsh_scan(const unsigned int* __restrict__ counts,
                                                unsigned int* __restrict__ starts){
  __shared__ unsigned int s[512];
  int bh = blockIdx.x, tid = threadIdx.x;
  unsigned int v = counts[bh * 512 + tid];
  s[tid] = v; __syncthreads();
  for (int off = 1; off < 512; off <<= 1){
    unsigned int add = (tid >= off) ? s[tid - off] : 0u;
    __syncthreads();
    s[tid] += add;
    __syncthreads();
  }
  starts[bh * 512 + tid] = s[tid] - v;
}

__global__ __launch_bounds__(256) void lsh_rank(const unsigned short* __restrict__ buckets,
                                                const unsigned int* __restrict__ starts,
                                                unsigned short* __restrict__ s2pos,
                                                unsigned short* __restrict__ pos2s){
  int bh = blockIdx.x >> 3, r = blockIdx.x & 7;
  __shared__ unsigned char lb[4096];
  __shared__ unsigned short cnt[64][4];
  const unsigned short* bsrc = buckets + (size_t)bh * TT + r * Tn;
  for (int t = threadIdx.x; t < 4096; t += 256) lb[t] = (unsigned char)(bsrc[t] - r * 64);
  __syncthreads();
  int b = threadIdx.x & 63, q = threadIdx.x >> 6;
  int c = 0;
  for (int t = q * 1024; t < (q + 1) * 1024; ++t) c += (lb[t] == b);
  cnt[b][q] = (unsigned short)c;
  __syncthreads();
  int off = 0;
  for (int q2 = 0; q2 < q; ++q2) off += cnt[b][q2];
  unsigned int run = starts[bh * 512 + r * 64 + b] + off;
  unsigned short* s2p = s2pos + (size_t)bh * TT;
  unsigned short* p2s = pos2s + (size_t)bh * TT + r * Tn;
  for (int t = q * 1024; t < (q + 1) * 1024; ++t){
    if (lb[t] == b){ s2p[run] = (unsigned short)t; p2s[t] = (unsigned short)run; run++; }
  }
}

#define KSTR 68
#define SWZ(row) ((((row) >> 3) & 7) << 2)

// ---------------- staging helper: 128 slot rows -> normalized swizzled LDS ------
DI void stage_rows(const float* __restrict__ qk, const unsigned short* __restrict__ s2pos,
                   int bh, int b, int h, int c, int cprev,
                   float* kbuf, float* den, unsigned short* kt){
  int j = threadIdx.x >> 1, half = threadIdx.x & 1;
  int slot = (j < 64) ? (c * 64 + j) : (cprev * 64 + (j - 64));
  int t = s2pos[(size_t)bh * TT + slot];
  const float* row = qk + ((size_t)(b * Tn + t) * En + h * Dn);
  int sw = SWZ(j);
  float tmp[32]; float ss = 0.f;
#pragma unroll
  for (int dd = 0; dd < 32; ++dd){ float xv = row[half * 32 + dd]; tmp[dd] = xv; ss = fmaf(xv, xv, ss); }
  ss += __shfl_xor(ss, 1);
  float dn = sqrtf(ss) + 1e-6f;
#pragma unroll
  for (int d4 = 0; d4 < 8; ++d4){
    float4 o; o.x = tmp[4*d4] / dn; o.y = tmp[4*d4+1] / dn; o.z = tmp[4*d4+2] / dn; o.w = tmp[4*d4+3] / dn;
    *(float4*)&kbuf[j * KSTR + ((half * 32 + 4 * d4) ^ sw)] = o;
  }
  if (!half){ den[j] = dn; kt[j] = (unsigned short)t; }
}

// ---------------- register-tiled dots: thread = 4q x 8k (swizzled reads) --------
DI void dots_tile(const float* kbuf, const float* den, const unsigned short* kt,
                  int a, int bb, float dots[4][8]){
  int swq = SWZ(4 * a);
  int swk = SWZ(8 * bb);
#pragma unroll
  for (int qq = 0; qq < 4; ++qq)
#pragma unroll
    for (int kk = 0; kk < 8; ++kk) dots[qq][kk] = 0.f;
#pragma unroll
  for (int d4 = 0; d4 < 16; ++d4){
    float4 qv[4], kv[8];
#pragma unroll
    for (int qq = 0; qq < 4; ++qq) qv[qq] = *(const float4*)&kbuf[(4*a+qq) * KSTR + ((d4 * 4) ^ swq)];
#pragma unroll
    for (int kk = 0; kk < 8; ++kk) kv[kk] = *(const float4*)&kbuf[(8*bb+kk) * KSTR + ((d4 * 4) ^ swk)];
#pragma unroll
    for (int qq = 0; qq < 4; ++qq)
#pragma unroll
      for (int kk = 0; kk < 8; ++kk){
        dots[qq][kk] = fmaf(qv[qq].x, kv[kk].x, dots[qq][kk]);
        dots[qq][kk] = fmaf(qv[qq].y, kv[kk].y, dots[qq][kk]);
        dots[qq][kk] = fmaf(qv[qq].z, kv[kk].z, dots[qq][kk]);
        dots[qq][kk] = fmaf(qv[qq].w, kv[kk].w, dots[qq][kk]);
      }
  }
#pragma unroll
  for (int qq = 0; qq < 4; ++qq){
    float sc = den[4*a+qq] * 0.125f;
    int qt = kt[4*a+qq];
#pragma unroll
    for (int kk = 0; kk < 8; ++kk){
      float v = dots[qq][kk] * sc;
      if ((int)kt[8*bb+kk] == qt) v = -1e5f;
      dots[qq][kk] = v;
    }
  }
}

// ---------------- pass 1: per-slot LSE (fallback path) ----------------
__global__ __launch_bounds__(256) void lsh_lse2(const float* __restrict__ qk,
                                                const unsigned short* __restrict__ s2pos,
                                                float* __restrict__ lse){
  int bh = blockIdx.x >> 9, c = blockIdx.x & 511;
  int b = bh >> 3, h = bh & 7;
  int cprev = (c + 511) & 511;
  __shared__ float kbuf[128 * KSTR];
  __shared__ float den[128];
  __shared__ unsigned short kt[128];
  __shared__ float red2[64][17];
  __shared__ float Marr[64];
  stage_rows(qk, s2pos, bh, b, h, c, cprev, kbuf, den, kt);
  __syncthreads();
  int a = threadIdx.x & 15, bb = threadIdx.x >> 4;
  float dots[4][8];
  dots_tile(kbuf, den, kt, a, bb, dots);
#pragma unroll
  for (int qq = 0; qq < 4; ++qq){
    float m = dots[qq][0];
#pragma unroll
    for (int kk = 1; kk < 8; ++kk) m = fmaxf(m, dots[qq][kk]);
    red2[4*a+qq][bb] = m;
  }
  __syncthreads();
  if (threadIdx.x < 64){
    float M = red2[threadIdx.x][0];
#pragma unroll
    for (int j = 1; j < 16; ++j) M = fmaxf(M, red2[threadIdx.x][j]);
    Marr[threadIdx.x] = M;
  }
  __syncthreads();
  float ssum[4];
#pragma unroll
  for (int qq = 0; qq < 4; ++qq){
    float M = Marr[4*a+qq];
    float s = 0.f;
#pragma unroll
    for (int kk = 0; kk < 8; ++kk) s += expf(dots[qq][kk] - M);
    ssum[qq] = s;
  }
  __syncthreads();
#pragma unroll
  for (int qq = 0; qq < 4; ++qq) red2[4*a+qq][bb] = ssum[qq];
  __syncthreads();
  if (threadIdx.x < 64){
    float S = 0.f;
#pragma unroll
    for (int j = 0; j < 16; ++j) S += red2[threadIdx.x][j];
    lse[(size_t)bh * TT + c * 64 + threadIdx.x] = Marr[threadIdx.x] + logf(S);
  }
}

// ---------------- per-(bh,t) round weights (fallback path) ----------------
__global__ __launch_bounds__(256) void lsh_wgt(const float* __restrict__ lse,
                                               const unsigned short* __restrict__ pos2s,
                                               float* __restrict__ wgt){
  int idx = blockIdx.x * 256 + threadIdx.x;
  int bh = idx >> 12, t = idx & 4095;
  float l[8];
#pragma unroll
  for (int r = 0; r < 8; ++r){
    int s = pos2s[(size_t)bh * TT + r * Tn + t];
    l[r] = lse[(size_t)bh * TT + s];
  }
  float M = l[0];
#pragma unroll
  for (int r = 1; r < 8; ++r) M = fmaxf(M, l[r]);
  float S = 0.f;
#pragma unroll
  for (int r = 0; r < 8; ++r) S += expf(l[r] - M);
  float L = M + logf(S);
#pragma unroll
  for (int r = 0; r < 8; ++r) wgt[(size_t)(bh * 8 + r) * Tn + t] = expf(l[r] - L);
}

// ---------------- fused pv: dots + in-block LSE + PV (two V halves) ------------
// Block decode XCD-swizzled: x = cc*16 + bh so x%8 == bh%8 (same-bh -> same XCD L2).
// LDS: kbuf 34.8K (K then P alias) + vhalf 17.4K (reduce scratch alias, then V
// rows 0..63, then rows 64..127) + den/kt -> ~53KB => 3 blocks/CU.
__global__ __launch_bounds__(256) void lsh_pv3(const float* __restrict__ qk,
                                               const float* __restrict__ vv,
                                               const unsigned short* __restrict__ s2pos,
                                               float* __restrict__ lse,
                                               float* __restrict__ so){
  int r = blockIdx.y;
  int bh = blockIdx.x & 15, cc = blockIdx.x >> 4;
  int c = r * 64 + cc, cprev = (c + 511) & 511;
  int b = bh >> 3, h = bh & 7;
  __shared__ float kbuf[128 * KSTR];          // aliased later as P[64][132]
  __shared__ float vhalf[64 * KSTR];          // head aliased as reduce scratch
  __shared__ float den[128];
  __shared__ unsigned short kt[128];
  float (*red2)[17] = (float(*)[17])vhalf;    // [64][17]
  float* Marr = vhalf + 64 * 17;              // [64]
  int tid = threadIdx.x;
  stage_rows(qk, s2pos, bh, b, h, c, cprev, kbuf, den, kt);
  __syncthreads();
  int a = tid & 15, bb = tid >> 4;
  float dots[4][8];
  dots_tile(kbuf, den, kt, a, bb, dots);
  // ---- in-block LSE ----
#pragma unroll
  for (int qq = 0; qq < 4; ++qq){
    float m = dots[qq][0];
#pragma unroll
    for (int kk = 1; kk < 8; ++kk) m = fmaxf(m, dots[qq][kk]);
    red2[4*a+qq][bb] = m;
  }
  __syncthreads();
  if (tid < 64){
    float M = red2[tid][0];
#pragma unroll
    for (int j = 1; j < 16; ++j) M = fmaxf(M, red2[tid][j]);
    Marr[tid] = M;
  }
  __syncthreads();
  float ssum[4];
#pragma unroll
  for (int qq = 0; qq < 4; ++qq){
    float M = Marr[4*a+qq];
    float s = 0.f;
#pragma unroll
    for (int kk = 0; kk < 8; ++kk) s += expf(dots[qq][kk] - M);
    ssum[qq] = s;
  }
  __syncthreads();
#pragma unroll
  for (int qq = 0; qq < 4; ++qq) red2[4*a+qq][bb] = ssum[qq];
  __syncthreads();
  if (tid < 64){
    float S = 0.f;
#pragma unroll
    for (int j = 0; j < 16; ++j) S += red2[tid][j];
    float lv = Marr[tid] + logf(S);
    lse[(size_t)bh * TT + c * 64 + tid] = lv;
    Marr[tid] = lv;                           // broadcast lse to all threads
  }
  __syncthreads();
  float lrow[4];
#pragma unroll
  for (int qq = 0; qq < 4; ++qq) lrow[qq] = Marr[4*a+qq];
#pragma unroll
  for (int qq = 0; qq < 4; ++qq)
#pragma unroll
    for (int kk = 0; kk < 8; ++kk) dots[qq][kk] = expf(dots[qq][kk] - lrow[qq]);
  __syncthreads();                            // reduce scratch + K reads done
  // ---- write P (swizzled) into kbuf alias; stage V rows 0..63 into vhalf ----
  float* pb = kbuf;
  {
    int swp = SWZ(4 * a);
#pragma unroll
    for (int qq = 0; qq < 4; ++qq){
      *(float4*)&pb[(4*a+qq) * 132 + ((8*bb)     ^ swp)] = make_float4(dots[qq][0], dots[qq][1], dots[qq][2], dots[qq][3]);
      *(float4*)&pb[(4*a+qq) * 132 + ((8*bb + 4) ^ swp)] = make_float4(dots[qq][4], dots[qq][5], dots[qq][6], dots[qq][7]);
    }
  }
  {
    int j = tid >> 2, quarter = tid & 3;      // rows 0..63, 4 thr/row
    int t = kt[j];
    int sw = SWZ(j);
    const float* row = vv + ((size_t)(b * Tn + t) * En + h * Dn);
#pragma unroll
    for (int d4 = 0; d4 < 4; ++d4){
      float4 o;
      o.x = row[quarter*16 + 4*d4]; o.y = row[quarter*16 + 4*d4 + 1];
      o.z = row[quarter*16 + 4*d4 + 2]; o.w = row[quarter*16 + 4*d4 + 3];
      *(float4*)&vhalf[j * KSTR + ((quarter * 16 + 4 * d4) ^ sw)] = o;
    }
  }
  __syncthreads();
  // ---- PV half 1: k4 in [0,16), V rows 0..63 ----
  int qg = tid & 15, dg = tid >> 4;
  float acc[4][4];
#pragma unroll
  for (int qq = 0; qq < 4; ++qq)
#pragma unroll
    for (int dd = 0; dd < 4; ++dd) acc[qq][dd] = 0.f;
  int swp = SWZ(4 * qg);
  for (int k4 = 0; k4 < 16; ++k4){
    int swv = SWZ(4 * k4);
    float4 pr[4], vr[4];
#pragma unroll
    for (int qq = 0; qq < 4; ++qq) pr[qq] = *(const float4*)&pb[(4*qg+qq) * 132 + ((k4 * 4) ^ swp)];
#pragma unroll
    for (int kk = 0; kk < 4; ++kk) vr[kk] = *(const float4*)&vhalf[(k4*4+kk) * KSTR + ((4*dg) ^ swv)];
#pragma unroll
    for (int kk = 0; kk < 4; ++kk){
#pragma unroll
      for (int qq = 0; qq < 4; ++qq){
        float p = (kk == 0) ? pr[qq].x : (kk == 1) ? pr[qq].y : (kk == 2) ? pr[qq].z : pr[qq].w;
        acc[qq][0] = fmaf(p, vr[kk].x, acc[qq][0]);
        acc[qq][1] = fmaf(p, vr[kk].y, acc[qq][1]);
        acc[qq][2] = fmaf(p, vr[kk].z, acc[qq][2]);
        acc[qq][3] = fmaf(p, vr[kk].w, acc[qq][3]);
      }
    }
  }
  __syncthreads();                            // done reading V half 1
  // ---- stage V rows 64..127 into vhalf ----
  {
    int j = 64 + (tid >> 2), quarter = tid & 3;
    int t = kt[j];
    int sw = SWZ(j);
    const float* row = vv + ((size_t)(b * Tn + t) * En + h * Dn);
#pragma unroll
    for (int d4 = 0; d4 < 4; ++d4){
      float4 o;
      o.x = row[quarter*16 + 4*d4]; o.y = row[quarter*16 + 4*d4 + 1];
      o.z = row[quarter*16 + 4*d4 + 2]; o.w = row[quarter*16 + 4*d4 + 3];
      *(float4*)&vhalf[(j - 64) * KSTR + ((quarter * 16 + 4 * d4) ^ sw)] = o;
    }
  }
  __syncthreads();
  // ---- PV half 2: k4 in [16,32), V rows 64..127 ----
  for (int k4 = 16; k4 < 32; ++k4){
    int swv = SWZ(4 * k4);
    float4 pr[4], vr[4];
#pragma unroll
    for (int qq = 0; qq < 4; ++qq) pr[qq] = *(const float4*)&pb[(4*qg+qq) * 132 + ((k4 * 4) ^ swp)];
#pragma unroll
    for (int kk = 0; kk < 4; ++kk) vr[kk] = *(const float4*)&vhalf[(k4*4+kk - 64) * KSTR + ((4*dg) ^ swv)];
#pragma unroll
    for (int kk = 0; kk < 4; ++kk){
#pragma unroll
      for (int qq = 0; qq < 4; ++qq){
        float p = (kk == 0) ? pr[qq].x : (kk == 1) ? pr[qq].y : (kk == 2) ? pr[qq].z : pr[qq].w;
        acc[qq][0] = fmaf(p, vr[kk].x, acc[qq][0]);
        acc[qq][1] = fmaf(p, vr[kk].y, acc[qq][1]);
        acc[qq][2] = fmaf(p, vr[kk].z, acc[qq][2]);
        acc[qq][3] = fmaf(p, vr[kk].w, acc[qq][3]);
      }
    }
  }
#pragma unroll
  for (int qq = 0; qq < 4; ++qq){
    int i = 4*qg + qq;
    int qt = kt[i];
    float* srow = so + (((size_t)(bh * 8 + r) * Tn) + qt) * Dn + 4*dg;
    *(float4*)srow = make_float4(acc[qq][0], acc[qq][1], acc[qq][2], acc[qq][3]);
  }
}

// ---------------- combine: attn[bh][t] = sum_r exp(lse_r - LSE) * so[r] --------
__global__ __launch_bounds__(256) void lsh_comb(const float* __restrict__ lse,
                                                const unsigned short* __restrict__ pos2s,
                                                const float* __restrict__ so,
                                                float* __restrict__ attn){
  int idx = blockIdx.x * 256 + threadIdx.x;   // 16*4096
  int bh = idx >> 12, t = idx & 4095;
  float l[8];
#pragma unroll
  for (int r = 0; r < 8; ++r){
    int s = pos2s[(size_t)bh * TT + r * Tn + t];
    l[r] = lse[(size_t)bh * TT + s];
  }
  float M = l[0];
#pragma unroll
  for (int r = 1; r < 8; ++r) M = fmaxf(M, l[r]);
  float S = 0.f;
#pragma unroll
  for (int r = 0; r < 8; ++r) S += expf(l[r] - M);
  float L = M + logf(S);
  float acc[64];
#pragma unroll
  for (int d = 0; d < 64; ++d) acc[d] = 0.f;
  for (int r = 0; r < 8; ++r){
    float w = expf(l[r] - L);
    const float* srow = so + (((size_t)(bh * 8 + r) * Tn) + t) * Dn;
#pragma unroll
    for (int d4 = 0; d4 < 16; ++d4){
      float4 v = *(const float4*)&srow[d4 * 4];
      acc[4*d4+0] = fmaf(w, v.x, acc[4*d4+0]);
      acc[4*d4+1] = fmaf(w, v.y, acc[4*d4+1]);
      acc[4*d4+2] = fmaf(w, v.z, acc[4*d4+2]);
      acc[4*d4+3] = fmaf(w, v.w, acc[4*d4+3]);
    }
  }
  float* arow = attn + ((size_t)(bh * Tn + t)) * Dn;
#pragma unroll
  for (int d4 = 0; d4 < 16; ++d4)
    *(float4*)&arow[d4 * 4] = make_float4(acc[4*d4], acc[4*d4+1], acc[4*d4+2], acc[4*d4+3]);
}

// ---------------- pass 2 (fallback): probs, PV, direct += ----------------
__global__ __launch_bounds__(256) void lsh_pv2(const float* __restrict__ qk,
                                               const float* __restrict__ vv,
                                               const unsigned short* __restrict__ s2pos,
                                               const float* __restrict__ lse,
                                               const float* __restrict__ wgt,
                                               float* __restrict__ attn, int r){
  int bh = blockIdx.x >> 6, cc = blockIdx.x & 63;
  int c = r * 64 + cc, cprev = (c + 511) & 511;
  int b = bh >> 3, h = bh & 7;
  __shared__ float kbuf[128 * KSTR];
  __shared__ float vbuf[128 * KSTR];
  __shared__ float den[128];
  __shared__ unsigned short kt[128];
  stage_rows(qk, s2pos, bh, b, h, c, cprev, kbuf, den, kt);
  __syncthreads();
  int a = threadIdx.x & 15, bb = threadIdx.x >> 4;
  float dots[4][8];
  dots_tile(kbuf, den, kt, a, bb, dots);
  float lrow[4];
#pragma unroll
  for (int qq = 0; qq < 4; ++qq) lrow[qq] = lse[(size_t)bh * TT + c * 64 + 4*a+qq];
#pragma unroll
  for (int qq = 0; qq < 4; ++qq)
#pragma unroll
    for (int kk = 0; kk < 8; ++kk) dots[qq][kk] = expf(dots[qq][kk] - lrow[qq]);
  __syncthreads();
  float* pb = kbuf;
  {
    int swp = SWZ(4 * a);
#pragma unroll
    for (int qq = 0; qq < 4; ++qq){
      *(float4*)&pb[(4*a+qq) * 132 + ((8*bb)     ^ swp)] = make_float4(dots[qq][0], dots[qq][1], dots[qq][2], dots[qq][3]);
      *(float4*)&pb[(4*a+qq) * 132 + ((8*bb + 4) ^ swp)] = make_float4(dots[qq][4], dots[qq][5], dots[qq][6], dots[qq][7]);
    }
  }
  {
    int j = threadIdx.x >> 1, half = threadIdx.x & 1;
    int t = kt[j];
    int sw = SWZ(j);
    const float* row = vv + ((size_t)(b * Tn + t) * En + h * Dn);
#pragma unroll
    for (int d4 = 0; d4 < 8; ++d4){
      float4 o;
      o.x = row[half*32 + 4*d4]; o.y = row[half*32 + 4*d4 + 1];
      o.z = row[half*32 + 4*d4 + 2]; o.w = row[half*32 + 4*d4 + 3];
      *(float4*)&vbuf[j * KSTR + ((half * 32 + 4 * d4) ^ sw)] = o;
    }
  }
  __syncthreads();
  int qg = threadIdx.x & 15, dg = threadIdx.x >> 4;
  float acc[4][4];
#pragma unroll
  for (int qq = 0; qq < 4; ++qq)
#pragma unroll
    for (int dd = 0; dd < 4; ++dd) acc[qq][dd] = 0.f;
  int swp = SWZ(4 * qg);
  for (int k4 = 0; k4 < 32; ++k4){
    int swv = SWZ(4 * k4);
    float4 pr[4], vr[4];
#pragma unroll
    for (int qq = 0; qq < 4; ++qq) pr[qq] = *(const float4*)&pb[(4*qg+qq) * 132 + ((k4 * 4) ^ swp)];
#pragma unroll
    for (int kk = 0; kk < 4; ++kk) vr[kk] = *(const float4*)&vbuf[(k4*4+kk) * KSTR + ((4*dg) ^ swv)];
#pragma unroll
    for (int kk = 0; kk < 4; ++kk){
#pragma unroll
      for (int qq = 0; qq < 4; ++qq){
        float p = (kk == 0) ? pr[qq].x : (kk == 1) ? pr[qq].y : (kk == 2) ? pr[qq].z : pr[qq].w;
        acc[qq][0] = fmaf(p, vr[kk].x, acc[qq][0]);
        acc[qq][1] = fmaf(p, vr[kk].y, acc[qq][1]);
        acc[qq][2] = fmaf(p, vr[kk].z, acc[qq][2]);
        acc[qq][3] = fmaf(p, vr[kk].w, acc[qq][3]);
      }
    }
  }
#pragma unroll
  for (int qq = 0; qq < 4; ++qq){
    int i = 4*qg + qq;
    int qt = kt[i];
    float w = wgt[(size_t)(bh * 8 + r) * Tn + qt];
    float* arow = attn + ((size_t)(bh * Tn + qt)) * Dn + 4*dg;
    float4 old = *(float4*)arow;
    old.x += w * acc[qq][0]; old.y += w * acc[qq][1];
    old.z += w * acc[qq][2]; old.w += w * acc[qq][3];
    *(float4*)arow = old;
  }
}

// ---------------- host ----------------
extern "C" void kernel_launch(void* const* d_in, const int* in_sizes, int n_in,
                              void* d_out, int out_size, void* d_ws, size_t ws_size,
                              hipStream_t stream){
  (void)in_sizes; (void)n_in; (void)out_size;
  const float* x    = (const float*)d_in[0];
  const float* wqk  = (const float*)d_in[1];
  const float* wv   = (const float*)d_in[2];
  const float* wout = (const float*)d_in[3];
  const float* bout = (const float*)d_in[4];
  float* out = (float*)d_out;
  char* ws = (char*)d_ws;

  size_t off = 0;
  auto alloc = [&](size_t n){ size_t o = off; off += (n + 255) & ~(size_t)255; return o; };
  float*          qk      = (float*)(ws + alloc(8192ull * 512 * 4));
  float*          vv      = (float*)(ws + alloc(8192ull * 512 * 4));
  float*          rot     = (float*)(ws + alloc(65536));
  unsigned short* buckets = (unsigned short*)(ws + alloc(16ull * TT * 2));
  unsigned int*   counts  = (unsigned int*)(ws + alloc(16ull * 512 * 4));
  unsigned int*   starts  = (unsigned int*)(ws + alloc(16ull * 512 * 4));
  unsigned short* s2pos   = (unsigned short*)(ws + alloc(16ull * TT * 2));
  unsigned short* pos2s   = (unsigned short*)(ws + alloc(16ull * TT * 2));
  float*          lse     = (float*)(ws + alloc(16ull * TT * 4));
  float*          wgt     = (float*)(ws + alloc(16ull * 8 * 4096 * 4));
  float*          attn    = (float*)(ws + alloc(16ull * 4096 * 64 * 4));
  size_t o_so = alloc(16ull * 8 * 4096 * 64 * 4);     // 134 MB
  bool fused = (off <= ws_size);
  float* so = (float*)(ws + o_so);

  hipMemsetAsync(counts, 0, 16ull * 512 * 4, stream);

  lsh_gemm_t<0, 320, false><<<dim3(128, 8), 256, 0, stream>>>(x, wqk, nullptr, qk);
  lsh_gemm_t<0, 320, true ><<<dim3(128, 8), 256, 0, stream>>>(x, wv,  nullptr, vv);
  lsh_gen_rot<<<dim3(64), 256, 0, stream>>>(rot);
  lsh_buckets3<<<dim3(16, 16, 8), 256, 0, stream>>>(qk, rot, buckets);
  lsh_hist<<<dim3(2048), 256, 0, stream>>>(buckets, counts);
  lsh_scan<<<dim3(16), 512, 0, stream>>>(counts, starts);
  lsh_rank<<<dim3(128), 256, 0, stream>>>(buckets, starts, s2pos, pos2s);
  if (fused){
    lsh_pv3<<<dim3(16 * 64, 8), 256, 0, stream>>>(qk, vv, s2pos, lse, so);
    lsh_comb<<<dim3(256), 256, 0, stream>>>(lse, pos2s, so, attn);
  } else {
    hipMemsetAsync(attn, 0, 16ull * 4096 * 64 * 4, stream);
    lsh_lse2<<<dim3(16 * 512), 256, 0, stream>>>(qk, s2pos, lse);
    lsh_wgt<<<dim3(256), 256, 0, stream>>>(lse, pos2s, wgt);
    for (int r = 0; r < 8; ++r)
      lsh_pv2<<<dim3(16 * 64), 256, 0, stream>>>(qk, vv, s2pos, lse, wgt, attn, r);
  }
  lsh_gemm_t<1, 320, true ><<<dim3(128, 8), 256, 0, stream>>>(attn, wout, bout, out);
}